// Round 1
// baseline (14307.211 us; speedup 1.0000x reference)
//
#include <hip/hip_runtime.h>
#include <stdint.h>

typedef unsigned short u16;
typedef unsigned int   u32;
typedef __attribute__((ext_vector_type(8))) short bf8v;          // 8 x bf16 MFMA frag (4 VGPR)
typedef __attribute__((ext_vector_type(4))) float f4v;           // MFMA acc frag
typedef __attribute__((ext_vector_type(8))) unsigned short us8v; // 16B bf16 vector

__device__ __forceinline__ float bfs(u16 u){ union { u32 i; float f; } v; v.i = ((u32)u) << 16; return v.f; }
__device__ __forceinline__ u16 f2bf(float f){ union { float f; u32 i; } v; v.f = f; u32 i = v.i; return (u16)((i + 0x7fffu + ((i >> 16) & 1u)) >> 16); }
__device__ __forceinline__ float sigm(float x){ return 1.f / (1.f + __expf(-x)); }
__device__ __forceinline__ float tanh_(float x){ float e = __expf(2.f * x); return 1.f - 2.f / (e + 1.f); }

// ---------------- one-time / chunked prep ----------------

// feature_map f32 (b,ci,hw) -> chunk bf16 (b_local,hw,ci), 64 batches at b_base
__global__ __launch_bounds__(256) void k_transpose_fm(const float* __restrict__ fm, u16* __restrict__ out, int b_base){
  __shared__ u16 tile[64][65];
  int b = blockIdx.z, hw0 = blockIdx.x * 64, ci0 = blockIdx.y * 64;
  int tid = threadIdx.x;
  int hwl = tid & 63, ci_l = tid >> 6;
  #pragma unroll
  for (int r = 0; r < 16; ++r){
    int ci = ci_l * 16 + r;
    tile[ci][hwl] = f2bf(fm[((size_t)((b_base + b) * 512 + ci0 + ci)) * 256 + hw0 + hwl]);
  }
  __syncthreads();
  int cil = tid & 63, hw_l = tid >> 6;
  #pragma unroll
  for (int r = 0; r < 16; ++r){
    int hw = hw_l * 16 + r;
    out[((size_t)(b * 256 + hw0 + hw)) * 512 + ci0 + cil] = tile[cil][hw];
  }
}

// conv_m2h_w f32 (co,ci,3,3) -> Wt bf16 (dydx,co,ci)
__global__ __launch_bounds__(256) void k_wt_prep(const float* __restrict__ w, u16* __restrict__ wt){
  int idx = blockIdx.x * 256 + threadIdx.x;         // 9*512*512
  int ci = idx & 511, co = (idx >> 9) & 511, dydx = idx >> 18;
  wt[idx] = f2bf(w[((size_t)(co * 512 + ci)) * 9 + dydx]);
}

// generic f32 -> bf16 convert (k-contiguous row-major weights)
__global__ __launch_bounds__(256) void k_cvt(const float* __restrict__ src, u16* __restrict__ dst, int n){
  int idx = blockIdx.x * 256 + threadIdx.x;
  if (idx < n) dst[idx] = f2bf(src[idx]);
}
// r1_wih (2048 x 550) -> first 512 cols, bf16 [2048][512]
__global__ __launch_bounds__(256) void k_cvt_rw1(const float* __restrict__ src, u16* __restrict__ dst){
  int idx = blockIdx.x * 256 + threadIdx.x;   // 2048*512
  int n = idx >> 9, k = idx & 511;
  dst[idx] = f2bf(src[(size_t)n * 550 + k]);
}
// gen_w (38 x 512) -> bf16 [48][512] zero-padded
__global__ __launch_bounds__(256) void k_cvt_gen(const float* __restrict__ src, u16* __restrict__ dst){
  int idx = blockIdx.x * 256 + threadIdx.x;   // 48*512
  int n = idx >> 9, k = idx & 511;
  dst[idx] = (n < 38) ? f2bf(src[(size_t)n * 512 + k]) : (u16)0;
}
// transpose-convert f32 [512][512] -> bf16 [512][512]^T  (dst[c][r] = src[r][c])
__global__ __launch_bounds__(256) void k_cvt_t(const float* __restrict__ src, u16* __restrict__ dst){
  __shared__ float tile[32][33];
  int c0 = blockIdx.x * 32, r0 = blockIdx.y * 32;
  int tx = threadIdx.x & 31, ty = threadIdx.x >> 5;
  #pragma unroll
  for (int rr = ty; rr < 32; rr += 8)
    tile[rr][tx] = src[(size_t)(r0 + rr) * 512 + c0 + tx];
  __syncthreads();
  #pragma unroll
  for (int rr = ty; rr < 32; rr += 8)
    dst[(size_t)(c0 + rr) * 512 + r0 + tx] = f2bf(tile[tx][rr]);
}
// out[n] = a1[n] (+a2[n]) + sum_k W[n][k]*vin[k]   (W row length 512)
__global__ __launch_bounds__(256) void k_bfold(const float* __restrict__ W, const float* __restrict__ vin,
    const float* __restrict__ a1, const float* __restrict__ a2, float* __restrict__ out, int N){
  int n = blockIdx.x * 256 + threadIdx.x;
  if (n >= N) return;
  float s = a1 ? a1[n] : 0.f;
  if (a2) s += a2[n];
  const float* wr = W + (size_t)n * 512;
  float acc0 = 0.f, acc1 = 0.f, acc2 = 0.f, acc3 = 0.f;
  for (int k = 0; k < 512; k += 4){
    acc0 = fmaf(wr[k],   vin[k],   acc0);
    acc1 = fmaf(wr[k+1], vin[k+1], acc1);
    acc2 = fmaf(wr[k+2], vin[k+2], acc2);
    acc3 = fmaf(wr[k+3], vin[k+3], acc3);
  }
  out[n] = s + ((acc0 + acc1) + (acc2 + acc3));
}
// dst[256][512] += row[512]
__global__ __launch_bounds__(256) void k_addrow(float* __restrict__ dst, const float* __restrict__ row){
  int idx = blockIdx.x * 256 + threadIdx.x;  // 131072
  dst[idx] += row[idx & 511];
}

// ---------------- conv3x3 as implicit GEMM (MFMA bf16) ----------------
// Per launch: 64 batches. M=16384, N=512, K=9*512. Tile 128x128, BK=32.
__global__ __launch_bounds__(256) void k_conv(
    const u16* __restrict__ in_t, const u16* __restrict__ Wt,
    const float* __restrict__ cbias, u16* __restrict__ fmh, int b_base)
{
  __shared__ u16 As[128 * 32];
  __shared__ u16 Bs[128 * 32];
  int tid = threadIdx.x;
  int wave = tid >> 6, lane = tid & 63;
  int nb = blockIdx.x & 3, mb = blockIdx.x >> 2;
  int m0 = mb * 128, n0 = nb * 128;
  int bb = m0 >> 8;
  int r = tid >> 1;
  int seg = (tid & 1) * 16;
  int hwl = (mb & 1) * 128 + r;
  int y = hwl >> 5, x = hwl & 31;
  const u16* aBase = in_t + ((size_t)bb * 256) * 512 + seg;
  const u16* bBase = Wt + ((size_t)(n0 + r)) * 512 + seg;
  int lm = lane & 15, quad = lane >> 4;
  int wm = (wave & 1) * 64, wn = (wave >> 1) * 64;
  f4v acc[4][4];
  #pragma unroll
  for (int i = 0; i < 4; ++i)
    #pragma unroll
    for (int j = 0; j < 4; ++j)
      acc[i][j] = (f4v){0.f, 0.f, 0.f, 0.f};

  for (int dydx = 0; dydx < 9; ++dydx){
    int dy = dydx / 3, dx = dydx - dy * 3;
    int yy = y + dy - 1, xx = x + dx - 1;
    bool ok = (yy >= 0) && (yy < 8) && (xx >= 0) && (xx < 32);
    const u16* aRow = aBase + (ptrdiff_t)(yy * 32 + xx) * 512;
    const u16* bRow = bBase + (size_t)dydx * 262144;
    for (int kc = 0; kc < 16; ++kc){
      us8v a0 = (us8v){0,0,0,0,0,0,0,0}, a1 = a0;
      if (ok){
        a0 = *(const us8v*)(aRow + kc * 32);
        a1 = *(const us8v*)(aRow + kc * 32 + 8);
      }
      us8v b0 = *(const us8v*)(bRow + kc * 32);
      us8v b1 = *(const us8v*)(bRow + kc * 32 + 8);
      __syncthreads();
      *(us8v*)&As[r * 32 + seg]     = a0;
      *(us8v*)&As[r * 32 + seg + 8] = a1;
      *(us8v*)&Bs[r * 32 + seg]     = b0;
      *(us8v*)&Bs[r * 32 + seg + 8] = b1;
      __syncthreads();
      bf8v af[4], bfr[4];
      #pragma unroll
      for (int i = 0; i < 4; ++i) af[i]  = *(const bf8v*)&As[(wm + i * 16 + lm) * 32 + quad * 8];
      #pragma unroll
      for (int j = 0; j < 4; ++j) bfr[j] = *(const bf8v*)&Bs[(wn + j * 16 + lm) * 32 + quad * 8];
      #pragma unroll
      for (int i = 0; i < 4; ++i)
        #pragma unroll
        for (int j = 0; j < 4; ++j)
          acc[i][j] = __builtin_amdgcn_mfma_f32_16x16x32_bf16(af[i], bfr[j], acc[i][j], 0, 0, 0);
    }
  }
  #pragma unroll
  for (int j = 0; j < 4; ++j){
    int co = n0 + wn + j * 16 + lm;
    float bv = cbias[co];
    #pragma unroll
    for (int i = 0; i < 4; ++i){
      int mrow = m0 + wm + i * 16 + quad * 4;
      int hw = mrow & 255;
      ushort4 pk;
      pk.x = f2bf(acc[i][j][0] + bv);
      pk.y = f2bf(acc[i][j][1] + bv);
      pk.z = f2bf(acc[i][j][2] + bv);
      pk.w = f2bf(acc[i][j][3] + bv);
      *(ushort4*)&fmh[((size_t)((b_base + bb) * 512 + co)) * 256 + hw] = pk;
    }
  }
}

// ---------------- MFMA recurrence GEMM ----------------
// OUT[M][N] = A1@W1^T (+A2@W2^T) + b1 + b2 + C0
// A*, W* bf16 k-contig (lda/ldw=512, K=512 per pass). grid(N/128, M/128), 256 thr.
__global__ __launch_bounds__(256) void k_mgemm(
    const u16* __restrict__ A1, const u16* __restrict__ W1,
    const u16* __restrict__ A2, const u16* __restrict__ W2,
    const float* __restrict__ b1, const float* __restrict__ b2,
    const float* __restrict__ C0,
    void* __restrict__ out, int obf16, int N)
{
  __shared__ u16 As[128 * 32];
  __shared__ u16 Bs[128 * 32];
  int tid = threadIdx.x;
  int wave = tid >> 6, lane = tid & 63;
  int m0 = blockIdx.y * 128, n0 = blockIdx.x * 128;
  int r = tid >> 1, seg = (tid & 1) * 16;
  int lm = lane & 15, quad = lane >> 4;
  int wm = (wave & 1) * 64, wn = (wave >> 1) * 64;
  f4v acc[4][4];
  #pragma unroll
  for (int i = 0; i < 4; ++i)
    #pragma unroll
    for (int j = 0; j < 4; ++j)
      acc[i][j] = (f4v){0.f, 0.f, 0.f, 0.f};

  for (int pass = 0; pass < 2; ++pass){
    const u16* A = pass ? A2 : A1;
    const u16* W = pass ? W2 : W1;
    if (!A) break;
    const u16* aRow = A + (size_t)(m0 + r) * 512 + seg;
    const u16* bRow = W + (size_t)(n0 + r) * 512 + seg;
    for (int kc = 0; kc < 16; ++kc){
      us8v a0 = *(const us8v*)(aRow + kc * 32);
      us8v a1 = *(const us8v*)(aRow + kc * 32 + 8);
      us8v b0 = *(const us8v*)(bRow + kc * 32);
      us8v b1 = *(const us8v*)(bRow + kc * 32 + 8);
      __syncthreads();
      *(us8v*)&As[r * 32 + seg]     = a0;
      *(us8v*)&As[r * 32 + seg + 8] = a1;
      *(us8v*)&Bs[r * 32 + seg]     = b0;
      *(us8v*)&Bs[r * 32 + seg + 8] = b1;
      __syncthreads();
      bf8v af[4], bfr[4];
      #pragma unroll
      for (int i = 0; i < 4; ++i) af[i]  = *(const bf8v*)&As[(wm + i * 16 + lm) * 32 + quad * 8];
      #pragma unroll
      for (int j = 0; j < 4; ++j) bfr[j] = *(const bf8v*)&Bs[(wn + j * 16 + lm) * 32 + quad * 8];
      #pragma unroll
      for (int i = 0; i < 4; ++i)
        #pragma unroll
        for (int j = 0; j < 4; ++j)
          acc[i][j] = __builtin_amdgcn_mfma_f32_16x16x32_bf16(af[i], bfr[j], acc[i][j], 0, 0, 0);
    }
  }
  #pragma unroll
  for (int j = 0; j < 4; ++j){
    int n = n0 + wn + j * 16 + lm;
    float badd = 0.f;
    if (b1) badd += b1[n];
    if (b2) badd += b2[n];
    #pragma unroll
    for (int i = 0; i < 4; ++i){
      int mb = m0 + wm + i * 16 + quad * 4;
      #pragma unroll
      for (int reg = 0; reg < 4; ++reg){
        int m = mb + reg;
        float v = acc[i][j][reg] + badd;
        if (C0) v += C0[(size_t)m * N + n];
        if (obf16) ((u16*)out)[(size_t)m * N + n] = f2bf(v);
        else       ((float*)out)[(size_t)m * N + n] = v;
      }
    }
  }
}

// ---------------- fused gates GEMM + LSTM ----------------
// Block = 64 batches (blockIdx.y) x 128 hidden cols (blockIdx.x). Wave w computes gate w
// (W rows w*512 + j0..j0+127) for all 64 batches. K = 512 per pass, 2 passes.
// Epilogue: cross-wave gate exchange via LDS (reusing Bs), LSTM pointwise, h/c/hid writes.
__global__ __launch_bounds__(256, 1) void k_glstm(
    const u16* __restrict__ A1, const u16* __restrict__ W1,
    const u16* __restrict__ A2, const u16* __restrict__ W2,
    const float* __restrict__ b1, const float* __restrict__ b2,
    const float* __restrict__ Woh, const int* __restrict__ txt, int t,
    u16* __restrict__ hn, float* __restrict__ c_io,
    u16* __restrict__ hidout)
{
  __shared__ u16 As[64 * 32];    // 4 KB
  __shared__ u16 Bs[512 * 32];   // 32 KB (reused as f32 gate-exchange in epilogue)
  int tid = threadIdx.x;
  int wave = tid >> 6, lane = tid & 63;
  int lm = lane & 15, quad = lane >> 4;
  int m0 = blockIdx.y * 64, j0 = blockIdx.x * 128;
  // A staging: row = tid&63, seg = (tid>>6)*8 (covers 64x32)
  int ar = tid & 63, aseg = (tid >> 6) * 8;
  // B staging: rows 2*tid, 2*tid+1 of the 512-row (4 gates x 128 j) tile
  int br0 = 2 * tid, br1 = br0 + 1;
  int wr0 = (br0 >> 7) * 512 + j0 + (br0 & 127);
  int wr1 = (br1 >> 7) * 512 + j0 + (br1 & 127);
  f4v acc[4][8];
  #pragma unroll
  for (int i = 0; i < 4; ++i)
    #pragma unroll
    for (int j = 0; j < 8; ++j)
      acc[i][j] = (f4v){0.f, 0.f, 0.f, 0.f};

  for (int pass = 0; pass < 2; ++pass){
    const u16* A = pass ? A2 : A1;
    const u16* W = pass ? W2 : W1;
    const u16* aP  = A + (size_t)(m0 + ar) * 512 + aseg;
    const u16* bP0 = W + (size_t)wr0 * 512;
    const u16* bP1 = W + (size_t)wr1 * 512;
    for (int kc = 0; kc < 16; ++kc){
      us8v av  = *(const us8v*)(aP + kc * 32);
      us8v b00 = *(const us8v*)(bP0 + kc * 32);
      us8v b01 = *(const us8v*)(bP0 + kc * 32 + 8);
      us8v b02 = *(const us8v*)(bP0 + kc * 32 + 16);
      us8v b03 = *(const us8v*)(bP0 + kc * 32 + 24);
      us8v b10 = *(const us8v*)(bP1 + kc * 32);
      us8v b11 = *(const us8v*)(bP1 + kc * 32 + 8);
      us8v b12 = *(const us8v*)(bP1 + kc * 32 + 16);
      us8v b13 = *(const us8v*)(bP1 + kc * 32 + 24);
      __syncthreads();
      *(us8v*)&As[ar * 32 + aseg] = av;
      *(us8v*)&Bs[br0 * 32]      = b00;
      *(us8v*)&Bs[br0 * 32 + 8]  = b01;
      *(us8v*)&Bs[br0 * 32 + 16] = b02;
      *(us8v*)&Bs[br0 * 32 + 24] = b03;
      *(us8v*)&Bs[br1 * 32]      = b10;
      *(us8v*)&Bs[br1 * 32 + 8]  = b11;
      *(us8v*)&Bs[br1 * 32 + 16] = b12;
      *(us8v*)&Bs[br1 * 32 + 24] = b13;
      __syncthreads();
      bf8v af[4], bfr[8];
      #pragma unroll
      for (int mi = 0; mi < 4; ++mi) af[mi]  = *(const bf8v*)&As[(mi * 16 + lm) * 32 + quad * 8];
      #pragma unroll
      for (int nj = 0; nj < 8; ++nj) bfr[nj] = *(const bf8v*)&Bs[(wave * 128 + nj * 16 + lm) * 32 + quad * 8];
      #pragma unroll
      for (int mi = 0; mi < 4; ++mi)
        #pragma unroll
        for (int nj = 0; nj < 8; ++nj)
          acc[mi][nj] = __builtin_amdgcn_mfma_f32_16x16x32_bf16(af[mi], bfr[nj], acc[mi][nj], 0, 0, 0);
    }
  }

  // epilogue in 4 chunks of 16 batch-rows: exchange gates through LDS, then LSTM
  float* gL = (float*)Bs;   // [4 gates][16 rows][128 cols] f32 = 32 KB
  for (int mi = 0; mi < 4; ++mi){
    __syncthreads();
    #pragma unroll
    for (int nj = 0; nj < 8; ++nj)
      #pragma unroll
      for (int reg = 0; reg < 4; ++reg)
        gL[wave * 2048 + (quad * 4 + reg) * 128 + nj * 16 + lm] = acc[mi][nj][reg];
    __syncthreads();
    #pragma unroll
    for (int p = 0; p < 8; ++p){
      int idx = p * 256 + tid;          // 16*128 = 2048 outputs
      int bl = idx >> 7, jj = idx & 127;
      int b = m0 + mi * 16 + bl;
      int j = j0 + jj;
      float gi = gL[idx];
      float gf = gL[2048 + idx];
      float gg = gL[4096 + idx];
      float go = gL[6144 + idx];
      if (b1){ gi += b1[j]; gf += b1[512 + j]; gg += b1[1024 + j]; go += b1[1536 + j]; }
      if (b2){ gi += b2[j]; gf += b2[512 + j]; gg += b2[1024 + j]; go += b2[1536 + j]; }
      if (Woh){
        int tx = txt[b * 26 + t];
        gi += Woh[(size_t)j * 550 + 512 + tx];
        gf += Woh[(size_t)(512 + j) * 550 + 512 + tx];
        gg += Woh[(size_t)(1024 + j) * 550 + 512 + tx];
        go += Woh[(size_t)(1536 + j) * 550 + 512 + tx];
      }
      float iv = sigm(gi), fv = sigm(gf), gv = tanh_(gg), ov = sigm(go);
      float c = fv * c_io[(size_t)b * 512 + j] + iv * gv;
      float h = ov * tanh_(c);
      c_io[(size_t)b * 512 + j] = c;
      u16 hb = f2bf(h);
      hn[(size_t)b * 512 + j] = hb;
      if (hidout) hidout[((size_t)(b * 26 + t)) * 512 + j] = hb;
    }
  }
}

// ---------------- small dense ops ----------------

__global__ __launch_bounds__(256) void k_meanH(const float* __restrict__ H, float* __restrict__ outm){
  int idx = blockIdx.x * 256 + threadIdx.x;  // 256*512
  int b = idx >> 9, k = idx & 511;
  float s = 0.f;
  #pragma unroll
  for (int t = 0; t < 26; ++t) s += H[((size_t)(b * 26 + t)) * 512 + k];
  outm[idx] = s * (1.f / 26.f);
}

// one-off f32 VALU GEMM: out[256][512] = A[256][512] @ W[512][512]^T (raw f32)
__global__ __launch_bounds__(256) void k_pgemm(const float* __restrict__ A, const float* __restrict__ W,
                                               float* __restrict__ out){
  __shared__ float As[32][33];
  __shared__ float Ws[64][33];
  int tid = threadIdx.x;
  int n0 = blockIdx.x * 64, m0 = blockIdx.y * 32;
  float acc[2][4] = {{0.f,0.f,0.f,0.f},{0.f,0.f,0.f,0.f}};
  int ml = (tid >> 4) * 2, nl = (tid & 15) * 4;
  int sm = tid >> 3, sk = (tid & 7) * 4;
  int wn = tid >> 2, wk = (tid & 3) * 8;
  for (int k0 = 0; k0 < 512; k0 += 32){
    __syncthreads();
    float4 av = *(const float4*)&A[(size_t)(m0 + sm) * 512 + k0 + sk];
    As[sm][sk] = av.x; As[sm][sk+1] = av.y; As[sm][sk+2] = av.z; As[sm][sk+3] = av.w;
    const float* wp = W + (size_t)(n0 + wn) * 512 + k0 + wk;
    #pragma unroll
    for (int u2 = 0; u2 < 8; ++u2) Ws[wn][wk + u2] = wp[u2];
    __syncthreads();
    #pragma unroll
    for (int k = 0; k < 32; ++k){
      float a0 = As[ml][k], a1 = As[ml+1][k];
      float w0 = Ws[nl][k], w1 = Ws[nl+1][k], w2 = Ws[nl+2][k], w3 = Ws[nl+3][k];
      acc[0][0] = fmaf(a0,w0,acc[0][0]); acc[0][1] = fmaf(a0,w1,acc[0][1]);
      acc[0][2] = fmaf(a0,w2,acc[0][2]); acc[0][3] = fmaf(a0,w3,acc[0][3]);
      acc[1][0] = fmaf(a1,w0,acc[1][0]); acc[1][1] = fmaf(a1,w1,acc[1][1]);
      acc[1][2] = fmaf(a1,w2,acc[1][2]); acc[1][3] = fmaf(a1,w3,acc[1][3]);
    }
  }
  #pragma unroll
  for (int i = 0; i < 2; ++i)
    #pragma unroll
    for (int j = 0; j < 4; ++j)
      out[(size_t)(m0 + ml + i) * 512 + n0 + nl + j] = acc[i][j];
}

__global__ __launch_bounds__(256) void k_init(const float* __restrict__ hh, const float* __restrict__ hc,
                                              u16* h1, float* c1, u16* h2, float* c2){
  int idx = blockIdx.x * 256 + threadIdx.x;  // 131072
  float h0 = 0.5f * (hh[idx] + hh[idx + 131072]);
  float c0 = 0.5f * (hc[idx] + hc[idx + 131072]);
  u16 hb = f2bf(h0);
  h1[idx] = hb; h2[idx] = hb; c1[idx] = c0; c2[idx] = c0;
}

// fused attention: e -> softmax -> context ; one block per batch. q bf16 in, ctx bf16 out.
__global__ __launch_bounds__(256) void k_attn(const u16* __restrict__ fmh,
    const u16* __restrict__ q, const float* __restrict__ sw, const float* __restrict__ sb,
    u16* __restrict__ ctx)
{
  __shared__ float qs[512], wss[512], sA[256], sR[256];
  int b = blockIdx.x, tid = threadIdx.x;
  qs[tid] = bfs(q[b * 512 + tid]); qs[tid + 256] = bfs(q[b * 512 + 256 + tid]);
  wss[tid] = sw[tid];              wss[tid + 256] = sw[tid + 256];
  __syncthreads();
  const u16* fb = fmh + (size_t)b * 512 * 256;
  float e0 = 0.f, e1 = 0.f, e2 = 0.f, e3 = 0.f;
  for (int c = 0; c < 512; c += 4){
    e0 = fmaf(tanh_(bfs(fb[(c+0)*256 + tid]) + qs[c+0]), wss[c+0], e0);
    e1 = fmaf(tanh_(bfs(fb[(c+1)*256 + tid]) + qs[c+1]), wss[c+1], e1);
    e2 = fmaf(tanh_(bfs(fb[(c+2)*256 + tid]) + qs[c+2]), wss[c+2], e2);
    e3 = fmaf(tanh_(bfs(fb[(c+3)*256 + tid]) + qs[c+3]), wss[c+3], e3);
  }
  float e = (e0 + e1) + (e2 + e3) + sb[0];
  sR[tid] = e; __syncthreads();
  #pragma unroll
  for (int off = 128; off > 0; off >>= 1){
    if (tid < off) sR[tid] = fmaxf(sR[tid], sR[tid + off]);
    __syncthreads();
  }
  float mx = sR[0]; __syncthreads();
  float ex = __expf(e - mx);
  sR[tid] = ex; __syncthreads();
  #pragma unroll
  for (int off = 128; off > 0; off >>= 1){
    if (tid < off) sR[tid] += sR[tid + off];
    __syncthreads();
  }
  float inv = 1.f / sR[0];
  sA[tid] = ex * inv; __syncthreads();
  #pragma unroll
  for (int cc = 0; cc < 2; ++cc){
    int c = tid + cc * 256;
    const u16* row = fb + (size_t)c * 256;
    float s0 = 0.f, s1 = 0.f;
    for (int h8 = 0; h8 < 32; h8 += 2){
      us8v va = *(const us8v*)(row + h8 * 8);
      us8v vb = *(const us8v*)(row + h8 * 8 + 8);
      #pragma unroll
      for (int u2 = 0; u2 < 8; ++u2){
        s0 = fmaf(sA[h8*8 + u2],     bfs(va[u2]), s0);
        s1 = fmaf(sA[h8*8 + 8 + u2], bfs(vb[u2]), s1);
      }
    }
    ctx[(size_t)b * 512 + c] = f2bf(s0 + s1);
  }
}

// final projection: out[6656][38] = hid @ genw^T + gen_b. Tile 128x48, grid 52.
__global__ __launch_bounds__(256) void k_gen(const u16* __restrict__ hid,
    const u16* __restrict__ genw, const float* __restrict__ gb, float* __restrict__ out)
{
  __shared__ u16 As[128 * 32];
  __shared__ u16 Bs[48 * 32];
  int tid = threadIdx.x;
  int wave = tid >> 6, lane = tid & 63;
  int m0 = blockIdx.x * 128;
  int r = tid >> 1, seg = (tid & 1) * 16;
  int lm = lane & 15, quad = lane >> 4;
  int mw = wave * 32;
  f4v acc[2][3];
  #pragma unroll
  for (int i = 0; i < 2; ++i)
    #pragma unroll
    for (int j = 0; j < 3; ++j)
      acc[i][j] = (f4v){0.f, 0.f, 0.f, 0.f};
  const u16* aRow = hid + (size_t)(m0 + r) * 512 + seg;
  const u16* bRow = genw + (size_t)r * 512 + seg;   // valid only tid<96
  for (int kc = 0; kc < 16; ++kc){
    us8v a0 = *(const us8v*)(aRow + kc * 32);
    us8v a1 = *(const us8v*)(aRow + kc * 32 + 8);
    us8v b0, b1;
    if (tid < 96){
      b0 = *(const us8v*)(bRow + kc * 32);
      b1 = *(const us8v*)(bRow + kc * 32 + 8);
    }
    __syncthreads();
    *(us8v*)&As[r * 32 + seg]     = a0;
    *(us8v*)&As[r * 32 + seg + 8] = a1;
    if (tid < 96){
      *(us8v*)&Bs[r * 32 + seg]     = b0;
      *(us8v*)&Bs[r * 32 + seg + 8] = b1;
    }
    __syncthreads();
    bf8v af[2], bfr[3];
    #pragma unroll
    for (int i = 0; i < 2; ++i) af[i]  = *(const bf8v*)&As[(mw + i * 16 + lm) * 32 + quad * 8];
    #pragma unroll
    for (int j = 0; j < 3; ++j) bfr[j] = *(const bf8v*)&Bs[(j * 16 + lm) * 32 + quad * 8];
    #pragma unroll
    for (int i = 0; i < 2; ++i)
      #pragma unroll
      for (int j = 0; j < 3; ++j)
        acc[i][j] = __builtin_amdgcn_mfma_f32_16x16x32_bf16(af[i], bfr[j], acc[i][j], 0, 0, 0);
  }
  #pragma unroll
  for (int j = 0; j < 3; ++j){
    int n = j * 16 + lm;
    if (n >= 38) continue;
    float bv = gb[n];
    #pragma unroll
    for (int i = 0; i < 2; ++i){
      int mb = m0 + mw + i * 16 + quad * 4;
      #pragma unroll
      for (int reg = 0; reg < 4; ++reg)
        out[(size_t)(mb + reg) * 38 + n] = acc[i][j][reg] + bv;
    }
  }
}

extern "C" void kernel_launch(void* const* d_in, const int* in_sizes, int n_in,
                              void* d_out, int out_size, void* d_ws, size_t ws_size,
                              hipStream_t stream)
{
  (void)in_sizes; (void)n_in; (void)out_size; (void)ws_size;
  const float* fm      = (const float*)d_in[0];
  const float* batchH  = (const float*)d_in[1];
  const float* hh      = (const float*)d_in[2];
  const float* hc      = (const float*)d_in[3];
  const int*   text    = (const int*)d_in[4];
  const float* i2h_w   = (const float*)d_in[5];
  const float* h2h_w   = (const float*)d_in[6];
  const float* h2h_b   = (const float*)d_in[7];
  const float* cm2h_w  = (const float*)d_in[8];
  const float* cm2h_b  = (const float*)d_in[9];
  const float* ch2h_w  = (const float*)d_in[10];
  const float* ch2h_b  = (const float*)d_in[11];
  const float* score_w = (const float*)d_in[12];
  const float* score_b = (const float*)d_in[13];
  const float* r1_wih  = (const float*)d_in[14];
  const float* r1_whh  = (const float*)d_in[15];
  const float* r1_bih  = (const float*)d_in[16];
  const float* r1_bhh  = (const float*)d_in[17];
  const float* hlin_w  = (const float*)d_in[18];
  const float* hlin_b  = (const float*)d_in[19];
  const float* r2_wih  = (const float*)d_in[20];
  const float* r2_whh  = (const float*)d_in[21];
  const float* r2_bih  = (const float*)d_in[22];
  const float* r2_bhh  = (const float*)d_in[23];
  const float* gen_w   = (const float*)d_in[24];
  const float* gen_b   = (const float*)d_in[25];

  // ---- workspace layout (within proven 88.6 MB budget) ----
  char* ws = (char*)d_ws;
  u16* fmh = (u16*)(ws + 0);                 // 67,108,864 B, live whole run
  char* R  = ws + 67108864;                  // 21,495,808 B multi-phase region
  // conv phase (R fully owned by conv staging):
  u16* Wt    = (u16*)(R + 0);                // 4,718,592
  u16* chunk = (u16*)(R + 4718592);          // 16,777,216
  // steady-state (post-conv):
  u16* r1wB  = (u16*)(R + 0);                // 2,097,152  r1_wih[:, :512] bf16
  u16* r1hB  = (u16*)(R + 2097152);          // 2,097,152  r1_whh bf16
  u16* r2hB  = (u16*)(R + 4194304);          // 2,097,152  r2_whh bf16
  u16* W2cB  = (u16*)(R + 6291456);          // 2,097,152  (r2_wih @ hlin_w) bf16
  u16* WqcB  = (u16*)(R + 8388608);          //   524,288  (W1x1 @ h2h_w) bf16
  float* q_const = (float*)(R + 8912896);    //   524,288  time-invariant q part (f32)
  u16* slotA = (u16*)(R + 9437184);          //   262,144  ctx (bf16); genw overlay at epilogue
  u16* qb    = (u16*)(R + 9699328);          //   262,144  q bf16
  u16* h1a   = (u16*)(R + 9961472);          //   262,144  h1 ping
  u16* h1b   = (u16*)(R + 10223616);         //   262,144  h1 pong
  u16* h2a   = (u16*)(R + 10485760);         //   262,144  h2 ping
  u16* h2b   = (u16*)(R + 10747904);         //   262,144  h2 pong
  float* c1  = (float*)(R + 11010048);       //   524,288
  float* c2  = (float*)(R + 11534336);       //   524,288
  float* b2c = (float*)(R + 12058624);       //     8,192  folded gates2 bias
  float* qbias = (float*)(R + 12066816);     //     2,048  folded q bias
  u16* hid   = (u16*)(R + 12068864);         // 6,815,744  (b,t,hs) bf16 -> ends 18,884,608
  // precompute-only temps (overlay hid region + free tail; dead before hid is written):
  u16* r2wB    = (u16*)(R + 12068864);       // 2,097,152  r2_wih bf16
  u16* hlinT   = (u16*)(R + 14166016);       //   524,288  hlin_w^T bf16
  u16* h2hT    = (u16*)(R + 14690304);       //   524,288  h2h_w^T bf16
  u16* ch2hB   = (u16*)(R + 15214592);       //   524,288  conv_h2h 1x1 bf16
  float* bh_mean = (float*)(R + 18884608);   //   524,288
  float* bh_proj = (float*)(R + 19408896);   //   524,288
  u16* genw  = slotA;                        //    49,152  (epilogue overlay)

  // ---- conv phase ----
  k_wt_prep<<<9216, 256, 0, stream>>>(cm2h_w, Wt);
  for (int rb = 0; rb < 4; ++rb){
    k_transpose_fm<<<dim3(4, 8, 64), 256, 0, stream>>>(fm, chunk, rb * 64);
    k_conv<<<512, 256, 0, stream>>>(chunk, Wt, cm2h_b, fmh, rb * 64);
  }
  // ---- weight converts (overwrite conv staging) ----
  k_cvt_rw1<<<4096, 256, 0, stream>>>(r1_wih, r1wB);
  k_cvt<<<4096, 256, 0, stream>>>(r1_whh, r1hB, 1048576);
  k_cvt<<<4096, 256, 0, stream>>>(r2_whh, r2hB, 1048576);
  k_cvt<<<4096, 256, 0, stream>>>(r2_wih, r2wB, 1048576);
  k_cvt<<<1024, 256, 0, stream>>>(ch2h_w, ch2hB, 262144);
  k_cvt_t<<<dim3(16, 16), 256, 0, stream>>>(hlin_w, hlinT);
  k_cvt_t<<<dim3(16, 16), 256, 0, stream>>>(h2h_w, h2hT);
  // ---- folded weights ----
  // W2c[n][m] = sum_k r2_wih[n][k] * hlin_w[k][m]
  k_mgemm<<<dim3(4, 16), 256, 0, stream>>>(r2wB, hlinT, nullptr, nullptr,
      nullptr, nullptr, nullptr, W2cB, 1, 512);
  // Wqc[n][m] = sum_k W1x1[n][k] * h2h_w[k][m]
  k_mgemm<<<dim3(4, 4), 256, 0, stream>>>(ch2hB, h2hT, nullptr, nullptr,
      nullptr, nullptr, nullptr, WqcB, 1, 512);
  // ---- prologue ----
  k_meanH<<<512, 256, 0, stream>>>(batchH, bh_mean);
  k_pgemm<<<dim3(8, 8), 256, 0, stream>>>(bh_mean, i2h_w, bh_proj);
  // qbias[n] = ch2h_b[n] + sum_k h2h_b[k]*W1x1[n][k]
  k_bfold<<<2, 256, 0, stream>>>(ch2h_w, h2h_b, ch2h_b, nullptr, qbias, 512);
  // q_const = bh_proj @ W1x1^T (exact f32) + qbias
  k_pgemm<<<dim3(8, 8), 256, 0, stream>>>(bh_proj, ch2h_w, q_const);
  k_addrow<<<512, 256, 0, stream>>>(q_const, qbias);
  // b2c[n] = r2_bih[n] + r2_bhh[n] + sum_k r2_wih[n][k]*hlin_b[k]
  k_bfold<<<8, 256, 0, stream>>>(r2_wih, hlin_b, r2_bih, r2_bhh, b2c, 2048);
  k_init<<<512, 256, 0, stream>>>(hh, hc, h1a, c1, h2a, c2);

  // ---- 26-step recurrence: 4 kernels/step ----
  for (int t = 0; t < 26; ++t){
    u16* h1i = (t & 1) ? h1b : h1a;
    u16* h1o = (t & 1) ? h1a : h1b;
    u16* h2i = (t & 1) ? h2b : h2a;
    u16* h2o = (t & 1) ? h2a : h2b;
    // q = q_const + h2 @ Wqc^T  -> qb (bf16)
    k_mgemm<<<dim3(4, 2), 256, 0, stream>>>(h2i, WqcB, nullptr, nullptr,
        nullptr, nullptr, q_const, qb, 1, 512);
    // attention -> ctx in slotA (bf16)
    k_attn<<<256, 256, 0, stream>>>(fmh, qb, score_w, score_b, slotA);
    // gates1+lstm1: ctx@r1_wih[:512]^T + h1@r1_whh^T + b_ih + b_bhh + onehot; LSTM -> h1o, c1
    k_glstm<<<dim3(4, 4), 256, 0, stream>>>(slotA, r1wB, h1i, r1hB,
        r1_bih, r1_bhh, r1_wih, text, t, h1o, c1, nullptr);
    // gates2+lstm2: h1@W2c^T + h2@r2_whh^T + b2c; LSTM -> h2o, c2, hid
    k_glstm<<<dim3(4, 4), 256, 0, stream>>>(h1o, W2cB, h2i, r2hB,
        b2c, nullptr, nullptr, nullptr, t, h2o, c2, hid);
  }
  // ---- final projection ----
  k_cvt_gen<<<96, 256, 0, stream>>>(gen_w, genw);
  k_gen<<<52, 256, 0, stream>>>(hid, genw, gen_b, (float*)d_out);
}

// Round 2
// 5205.943 us; speedup vs baseline: 2.7482x; 2.7482x over previous
//
#include <hip/hip_runtime.h>
#include <stdint.h>

typedef unsigned short u16;
typedef unsigned int   u32;
typedef __attribute__((ext_vector_type(8))) short bf8v;          // 8 x bf16 MFMA frag (4 VGPR)
typedef __attribute__((ext_vector_type(4))) float f4v;           // MFMA acc frag
typedef __attribute__((ext_vector_type(8))) unsigned short us8v; // 16B bf16 vector

__device__ __forceinline__ float bfs(u16 u){ union { u32 i; float f; } v; v.i = ((u32)u) << 16; return v.f; }
__device__ __forceinline__ u16 f2bf(float f){ union { float f; u32 i; } v; v.f = f; u32 i = v.i; return (u16)((i + 0x7fffu + ((i >> 16) & 1u)) >> 16); }
__device__ __forceinline__ float sigm(float x){ return 1.f / (1.f + __expf(-x)); }
__device__ __forceinline__ float tanh_(float x){ float e = __expf(2.f * x); return 1.f - 2.f / (e + 1.f); }

// ---------------- one-time / chunked prep ----------------

// feature_map f32 (b,ci,hw) -> chunk bf16 (b_local,hw,ci), 64 batches at b_base
__global__ __launch_bounds__(256) void k_transpose_fm(const float* __restrict__ fm, u16* __restrict__ out, int b_base){
  __shared__ u16 tile[64][65];
  int b = blockIdx.z, hw0 = blockIdx.x * 64, ci0 = blockIdx.y * 64;
  int tid = threadIdx.x;
  int hwl = tid & 63, ci_l = tid >> 6;
  #pragma unroll
  for (int r = 0; r < 16; ++r){
    int ci = ci_l * 16 + r;
    tile[ci][hwl] = f2bf(fm[((size_t)((b_base + b) * 512 + ci0 + ci)) * 256 + hw0 + hwl]);
  }
  __syncthreads();
  int cil = tid & 63, hw_l = tid >> 6;
  #pragma unroll
  for (int r = 0; r < 16; ++r){
    int hw = hw_l * 16 + r;
    out[((size_t)(b * 256 + hw0 + hw)) * 512 + ci0 + cil] = tile[cil][hw];
  }
}

// conv_m2h_w f32 (co,ci,3,3) -> Wt bf16 (dydx,co,ci)
__global__ __launch_bounds__(256) void k_wt_prep(const float* __restrict__ w, u16* __restrict__ wt){
  int idx = blockIdx.x * 256 + threadIdx.x;         // 9*512*512
  int ci = idx & 511, co = (idx >> 9) & 511, dydx = idx >> 18;
  wt[idx] = f2bf(w[((size_t)(co * 512 + ci)) * 9 + dydx]);
}

// generic f32 -> bf16 convert (k-contiguous row-major weights)
__global__ __launch_bounds__(256) void k_cvt(const float* __restrict__ src, u16* __restrict__ dst, int n){
  int idx = blockIdx.x * 256 + threadIdx.x;
  if (idx < n) dst[idx] = f2bf(src[idx]);
}
// r1_wih (2048 x 550) -> first 512 cols, bf16 [2048][512]
__global__ __launch_bounds__(256) void k_cvt_rw1(const float* __restrict__ src, u16* __restrict__ dst){
  int idx = blockIdx.x * 256 + threadIdx.x;   // 2048*512
  int n = idx >> 9, k = idx & 511;
  dst[idx] = f2bf(src[(size_t)n * 550 + k]);
}
// gen_w (38 x 512) -> bf16 [48][512] zero-padded
__global__ __launch_bounds__(256) void k_cvt_gen(const float* __restrict__ src, u16* __restrict__ dst){
  int idx = blockIdx.x * 256 + threadIdx.x;   // 48*512
  int n = idx >> 9, k = idx & 511;
  dst[idx] = (n < 38) ? f2bf(src[(size_t)n * 512 + k]) : (u16)0;
}
// transpose-convert f32 [512][512] -> bf16 [512][512]^T  (dst[c][r] = src[r][c])
__global__ __launch_bounds__(256) void k_cvt_t(const float* __restrict__ src, u16* __restrict__ dst){
  __shared__ float tile[32][33];
  int c0 = blockIdx.x * 32, r0 = blockIdx.y * 32;
  int tx = threadIdx.x & 31, ty = threadIdx.x >> 5;
  #pragma unroll
  for (int rr = ty; rr < 32; rr += 8)
    tile[rr][tx] = src[(size_t)(r0 + rr) * 512 + c0 + tx];
  __syncthreads();
  #pragma unroll
  for (int rr = ty; rr < 32; rr += 8)
    dst[(size_t)(c0 + rr) * 512 + r0 + tx] = f2bf(tile[tx][rr]);
}
// out[n] = a1[n] (+a2[n]) + sum_k W[n][k]*vin[k]   (W row length 512)
__global__ __launch_bounds__(256) void k_bfold(const float* __restrict__ W, const float* __restrict__ vin,
    const float* __restrict__ a1, const float* __restrict__ a2, float* __restrict__ out, int N){
  int n = blockIdx.x * 256 + threadIdx.x;
  if (n >= N) return;
  float s = a1 ? a1[n] : 0.f;
  if (a2) s += a2[n];
  const float* wr = W + (size_t)n * 512;
  float acc0 = 0.f, acc1 = 0.f, acc2 = 0.f, acc3 = 0.f;
  for (int k = 0; k < 512; k += 4){
    acc0 = fmaf(wr[k],   vin[k],   acc0);
    acc1 = fmaf(wr[k+1], vin[k+1], acc1);
    acc2 = fmaf(wr[k+2], vin[k+2], acc2);
    acc3 = fmaf(wr[k+3], vin[k+3], acc3);
  }
  out[n] = s + ((acc0 + acc1) + (acc2 + acc3));
}
// dst[256][512] += row[512]
__global__ __launch_bounds__(256) void k_addrow(float* __restrict__ dst, const float* __restrict__ row){
  int idx = blockIdx.x * 256 + threadIdx.x;  // 131072
  dst[idx] += row[idx & 511];
}

// ---------------- conv3x3 as implicit GEMM (MFMA bf16) ----------------
// Per launch: 64 batches. M=16384, N=512, K=9*512. Tile 128x128, BK=32.
__global__ __launch_bounds__(256) void k_conv(
    const u16* __restrict__ in_t, const u16* __restrict__ Wt,
    const float* __restrict__ cbias, u16* __restrict__ fmh, int b_base)
{
  __shared__ u16 As[128 * 32];
  __shared__ u16 Bs[128 * 32];
  int tid = threadIdx.x;
  int wave = tid >> 6, lane = tid & 63;
  int nb = blockIdx.x & 3, mb = blockIdx.x >> 2;
  int m0 = mb * 128, n0 = nb * 128;
  int bb = m0 >> 8;
  int r = tid >> 1;
  int seg = (tid & 1) * 16;
  int hwl = (mb & 1) * 128 + r;
  int y = hwl >> 5, x = hwl & 31;
  const u16* aBase = in_t + ((size_t)bb * 256) * 512 + seg;
  const u16* bBase = Wt + ((size_t)(n0 + r)) * 512 + seg;
  int lm = lane & 15, quad = lane >> 4;
  int wm = (wave & 1) * 64, wn = (wave >> 1) * 64;
  f4v acc[4][4];
  #pragma unroll
  for (int i = 0; i < 4; ++i)
    #pragma unroll
    for (int j = 0; j < 4; ++j)
      acc[i][j] = (f4v){0.f, 0.f, 0.f, 0.f};

  for (int dydx = 0; dydx < 9; ++dydx){
    int dy = dydx / 3, dx = dydx - dy * 3;
    int yy = y + dy - 1, xx = x + dx - 1;
    bool ok = (yy >= 0) && (yy < 8) && (xx >= 0) && (xx < 32);
    const u16* aRow = aBase + (ptrdiff_t)(yy * 32 + xx) * 512;
    const u16* bRow = bBase + (size_t)dydx * 262144;
    for (int kc = 0; kc < 16; ++kc){
      us8v a0 = (us8v){0,0,0,0,0,0,0,0}, a1 = a0;
      if (ok){
        a0 = *(const us8v*)(aRow + kc * 32);
        a1 = *(const us8v*)(aRow + kc * 32 + 8);
      }
      us8v b0 = *(const us8v*)(bRow + kc * 32);
      us8v b1 = *(const us8v*)(bRow + kc * 32 + 8);
      __syncthreads();
      *(us8v*)&As[r * 32 + seg]     = a0;
      *(us8v*)&As[r * 32 + seg + 8] = a1;
      *(us8v*)&Bs[r * 32 + seg]     = b0;
      *(us8v*)&Bs[r * 32 + seg + 8] = b1;
      __syncthreads();
      bf8v af[4], bfr[4];
      #pragma unroll
      for (int i = 0; i < 4; ++i) af[i]  = *(const bf8v*)&As[(wm + i * 16 + lm) * 32 + quad * 8];
      #pragma unroll
      for (int j = 0; j < 4; ++j) bfr[j] = *(const bf8v*)&Bs[(wn + j * 16 + lm) * 32 + quad * 8];
      #pragma unroll
      for (int i = 0; i < 4; ++i)
        #pragma unroll
        for (int j = 0; j < 4; ++j)
          acc[i][j] = __builtin_amdgcn_mfma_f32_16x16x32_bf16(af[i], bfr[j], acc[i][j], 0, 0, 0);
    }
  }
  #pragma unroll
  for (int j = 0; j < 4; ++j){
    int co = n0 + wn + j * 16 + lm;
    float bv = cbias[co];
    #pragma unroll
    for (int i = 0; i < 4; ++i){
      int mrow = m0 + wm + i * 16 + quad * 4;
      int hw = mrow & 255;
      ushort4 pk;
      pk.x = f2bf(acc[i][j][0] + bv);
      pk.y = f2bf(acc[i][j][1] + bv);
      pk.z = f2bf(acc[i][j][2] + bv);
      pk.w = f2bf(acc[i][j][3] + bv);
      *(ushort4*)&fmh[((size_t)((b_base + bb) * 512 + co)) * 256 + hw] = pk;
    }
  }
}

// ---------------- MFMA recurrence GEMM ----------------
// OUT[M][N] = A1@W1^T (+A2@W2^T) + b1 + b2 + C0
// A*, W* bf16 k-contig (lda/ldw=512, K=512 per pass). grid(N/128, M/128), 256 thr.
__global__ __launch_bounds__(256) void k_mgemm(
    const u16* __restrict__ A1, const u16* __restrict__ W1,
    const u16* __restrict__ A2, const u16* __restrict__ W2,
    const float* __restrict__ b1, const float* __restrict__ b2,
    const float* __restrict__ C0,
    void* __restrict__ out, int obf16, int N)
{
  __shared__ u16 As[128 * 32];
  __shared__ u16 Bs[128 * 32];
  int tid = threadIdx.x;
  int wave = tid >> 6, lane = tid & 63;
  int m0 = blockIdx.y * 128, n0 = blockIdx.x * 128;
  int r = tid >> 1, seg = (tid & 1) * 16;
  int lm = lane & 15, quad = lane >> 4;
  int wm = (wave & 1) * 64, wn = (wave >> 1) * 64;
  f4v acc[4][4];
  #pragma unroll
  for (int i = 0; i < 4; ++i)
    #pragma unroll
    for (int j = 0; j < 4; ++j)
      acc[i][j] = (f4v){0.f, 0.f, 0.f, 0.f};

  for (int pass = 0; pass < 2; ++pass){
    const u16* A = pass ? A2 : A1;
    const u16* W = pass ? W2 : W1;
    if (!A) break;
    const u16* aRow = A + (size_t)(m0 + r) * 512 + seg;
    const u16* bRow = W + (size_t)(n0 + r) * 512 + seg;
    for (int kc = 0; kc < 16; ++kc){
      us8v a0 = *(const us8v*)(aRow + kc * 32);
      us8v a1 = *(const us8v*)(aRow + kc * 32 + 8);
      us8v b0 = *(const us8v*)(bRow + kc * 32);
      us8v b1 = *(const us8v*)(bRow + kc * 32 + 8);
      __syncthreads();
      *(us8v*)&As[r * 32 + seg]     = a0;
      *(us8v*)&As[r * 32 + seg + 8] = a1;
      *(us8v*)&Bs[r * 32 + seg]     = b0;
      *(us8v*)&Bs[r * 32 + seg + 8] = b1;
      __syncthreads();
      bf8v af[4], bfr[4];
      #pragma unroll
      for (int i = 0; i < 4; ++i) af[i]  = *(const bf8v*)&As[(wm + i * 16 + lm) * 32 + quad * 8];
      #pragma unroll
      for (int j = 0; j < 4; ++j) bfr[j] = *(const bf8v*)&Bs[(wn + j * 16 + lm) * 32 + quad * 8];
      #pragma unroll
      for (int i = 0; i < 4; ++i)
        #pragma unroll
        for (int j = 0; j < 4; ++j)
          acc[i][j] = __builtin_amdgcn_mfma_f32_16x16x32_bf16(af[i], bfr[j], acc[i][j], 0, 0, 0);
    }
  }
  #pragma unroll
  for (int j = 0; j < 4; ++j){
    int n = n0 + wn + j * 16 + lm;
    float badd = 0.f;
    if (b1) badd += b1[n];
    if (b2) badd += b2[n];
    #pragma unroll
    for (int i = 0; i < 4; ++i){
      int mb = m0 + wm + i * 16 + quad * 4;
      #pragma unroll
      for (int reg = 0; reg < 4; ++reg){
        int m = mb + reg;
        float v = acc[i][j][reg] + badd;
        if (C0) v += C0[(size_t)m * N + n];
        if (obf16) ((u16*)out)[(size_t)m * N + n] = f2bf(v);
        else       ((float*)out)[(size_t)m * N + n] = v;
      }
    }
  }
}

// ---------------- fused gates GEMM + LSTM (v2) ----------------
// Block = 64 batches (blockIdx.y) x 64 hidden cols (blockIdx.x). Wave w computes gate w
// (W rows w*512 + j0..j0+63) for all 64 batches. grid(8,4)=32 blocks. K=512/pass, 2 passes.
// Staging is conflict-free: thread t writes LDS byte t*16 within each 4KB panel.
// Epilogue fully unrolled (static acc indexing — rule #20), LDS gate exchange, LSTM.
__global__ __launch_bounds__(256, 1) void k_glstm(
    const u16* __restrict__ A1, const u16* __restrict__ W1,
    const u16* __restrict__ A2, const u16* __restrict__ W2,
    const float* __restrict__ b1, const float* __restrict__ b2,
    const float* __restrict__ Woh, const int* __restrict__ txt, int t,
    u16* __restrict__ hn, float* __restrict__ c_io,
    u16* __restrict__ hidout)
{
  __shared__ u16 As[64 * 32];    // 4 KB
  __shared__ u16 Bs[256 * 32];   // 16 KB (f32 gate-exchange in epilogue)
  int tid = threadIdx.x;
  int wave = tid >> 6, lane = tid & 63;
  int lm = lane & 15, quad = lane >> 4;
  int m0 = blockIdx.y * 64, j0 = blockIdx.x * 64;
  int sr = tid >> 2;            // 0..63 : staged row within panel
  int sseg = (tid & 3) * 8;     // u16 offset within 32-elem k-chunk
  f4v acc[4][4];
  #pragma unroll
  for (int i = 0; i < 4; ++i)
    #pragma unroll
    for (int j = 0; j < 4; ++j)
      acc[i][j] = (f4v){0.f, 0.f, 0.f, 0.f};

  for (int pass = 0; pass < 2; ++pass){
    const u16* A = pass ? A2 : A1;
    const u16* W = pass ? W2 : W1;
    const u16* aP  = A + (size_t)(m0 + sr) * 512 + sseg;
    const u16* bP0 = W + (size_t)(0 * 512 + j0 + sr) * 512 + sseg;
    const u16* bP1 = W + (size_t)(1 * 512 + j0 + sr) * 512 + sseg;
    const u16* bP2 = W + (size_t)(2 * 512 + j0 + sr) * 512 + sseg;
    const u16* bP3 = W + (size_t)(3 * 512 + j0 + sr) * 512 + sseg;
    for (int kc = 0; kc < 16; ++kc){
      us8v av  = *(const us8v*)(aP  + kc * 32);
      us8v bv0 = *(const us8v*)(bP0 + kc * 32);
      us8v bv1 = *(const us8v*)(bP1 + kc * 32);
      us8v bv2 = *(const us8v*)(bP2 + kc * 32);
      us8v bv3 = *(const us8v*)(bP3 + kc * 32);
      __syncthreads();
      *(us8v*)&As[sr * 32 + sseg]              = av;   // byte tid*16: conflict-free
      *(us8v*)&Bs[(0 * 64 + sr) * 32 + sseg]   = bv0;  // byte tid*16 within panel 0
      *(us8v*)&Bs[(1 * 64 + sr) * 32 + sseg]   = bv1;
      *(us8v*)&Bs[(2 * 64 + sr) * 32 + sseg]   = bv2;
      *(us8v*)&Bs[(3 * 64 + sr) * 32 + sseg]   = bv3;
      __syncthreads();
      bf8v af[4], bfr[4];
      #pragma unroll
      for (int mi = 0; mi < 4; ++mi) af[mi]  = *(const bf8v*)&As[(mi * 16 + lm) * 32 + quad * 8];
      #pragma unroll
      for (int nj = 0; nj < 4; ++nj) bfr[nj] = *(const bf8v*)&Bs[(wave * 64 + nj * 16 + lm) * 32 + quad * 8];
      #pragma unroll
      for (int mi = 0; mi < 4; ++mi)
        #pragma unroll
        for (int nj = 0; nj < 4; ++nj)
          acc[mi][nj] = __builtin_amdgcn_mfma_f32_16x16x32_bf16(af[mi], bfr[nj], acc[mi][nj], 0, 0, 0);
    }
  }

  // epilogue: 4 chunks of 16 batch-rows; gate exchange via LDS; fully unrolled
  float* gL = (float*)Bs;   // [4 gates][16 rows][64 cols] f32 = 16 KB
  #pragma unroll
  for (int mi = 0; mi < 4; ++mi){
    __syncthreads();
    #pragma unroll
    for (int nj = 0; nj < 4; ++nj)
      #pragma unroll
      for (int reg = 0; reg < 4; ++reg)
        gL[wave * 1024 + (quad * 4 + reg) * 64 + nj * 16 + lm] = acc[mi][nj][reg];
    __syncthreads();
    #pragma unroll
    for (int p = 0; p < 4; ++p){
      int idx = p * 256 + tid;          // 16*64 = 1024 outputs
      int bl = idx >> 6, jj = idx & 63;
      int b = m0 + mi * 16 + bl;
      int j = j0 + jj;
      float gi = gL[idx];
      float gf = gL[1024 + idx];
      float gg = gL[2048 + idx];
      float go = gL[3072 + idx];
      if (b1){ gi += b1[j]; gf += b1[512 + j]; gg += b1[1024 + j]; go += b1[1536 + j]; }
      if (b2){ gi += b2[j]; gf += b2[512 + j]; gg += b2[1024 + j]; go += b2[1536 + j]; }
      if (Woh){
        int tx = txt[b * 26 + t];
        gi += Woh[(size_t)j * 550 + 512 + tx];
        gf += Woh[(size_t)(512 + j) * 550 + 512 + tx];
        gg += Woh[(size_t)(1024 + j) * 550 + 512 + tx];
        go += Woh[(size_t)(1536 + j) * 550 + 512 + tx];
      }
      float iv = sigm(gi), fv = sigm(gf), gv = tanh_(gg), ov = sigm(go);
      float c = fv * c_io[(size_t)b * 512 + j] + iv * gv;
      float h = ov * tanh_(c);
      c_io[(size_t)b * 512 + j] = c;
      u16 hb = f2bf(h);
      hn[(size_t)b * 512 + j] = hb;
      if (hidout) hidout[((size_t)(b * 26 + t)) * 512 + j] = hb;
    }
  }
}

// ---------------- small dense ops ----------------

__global__ __launch_bounds__(256) void k_meanH(const float* __restrict__ H, float* __restrict__ outm){
  int idx = blockIdx.x * 256 + threadIdx.x;  // 256*512
  int b = idx >> 9, k = idx & 511;
  float s = 0.f;
  #pragma unroll
  for (int t = 0; t < 26; ++t) s += H[((size_t)(b * 26 + t)) * 512 + k];
  outm[idx] = s * (1.f / 26.f);
}

// one-off f32 VALU GEMM: out[256][512] = A[256][512] @ W[512][512]^T (raw f32)
__global__ __launch_bounds__(256) void k_pgemm(const float* __restrict__ A, const float* __restrict__ W,
                                               float* __restrict__ out){
  __shared__ float As[32][33];
  __shared__ float Ws[64][33];
  int tid = threadIdx.x;
  int n0 = blockIdx.x * 64, m0 = blockIdx.y * 32;
  float acc[2][4] = {{0.f,0.f,0.f,0.f},{0.f,0.f,0.f,0.f}};
  int ml = (tid >> 4) * 2, nl = (tid & 15) * 4;
  int sm = tid >> 3, sk = (tid & 7) * 4;
  int wn = tid >> 2, wk = (tid & 3) * 8;
  for (int k0 = 0; k0 < 512; k0 += 32){
    __syncthreads();
    float4 av = *(const float4*)&A[(size_t)(m0 + sm) * 512 + k0 + sk];
    As[sm][sk] = av.x; As[sm][sk+1] = av.y; As[sm][sk+2] = av.z; As[sm][sk+3] = av.w;
    const float* wp = W + (size_t)(n0 + wn) * 512 + k0 + wk;
    #pragma unroll
    for (int u2 = 0; u2 < 8; ++u2) Ws[wn][wk + u2] = wp[u2];
    __syncthreads();
    #pragma unroll
    for (int k = 0; k < 32; ++k){
      float a0 = As[ml][k], a1 = As[ml+1][k];
      float w0 = Ws[nl][k], w1 = Ws[nl+1][k], w2 = Ws[nl+2][k], w3 = Ws[nl+3][k];
      acc[0][0] = fmaf(a0,w0,acc[0][0]); acc[0][1] = fmaf(a0,w1,acc[0][1]);
      acc[0][2] = fmaf(a0,w2,acc[0][2]); acc[0][3] = fmaf(a0,w3,acc[0][3]);
      acc[1][0] = fmaf(a1,w0,acc[1][0]); acc[1][1] = fmaf(a1,w1,acc[1][1]);
      acc[1][2] = fmaf(a1,w2,acc[1][2]); acc[1][3] = fmaf(a1,w3,acc[1][3]);
    }
  }
  #pragma unroll
  for (int i = 0; i < 2; ++i)
    #pragma unroll
    for (int j = 0; j < 4; ++j)
      out[(size_t)(m0 + ml + i) * 512 + n0 + nl + j] = acc[i][j];
}

__global__ __launch_bounds__(256) void k_init(const float* __restrict__ hh, const float* __restrict__ hc,
                                              u16* h1, float* c1, u16* h2, float* c2){
  int idx = blockIdx.x * 256 + threadIdx.x;  // 131072
  float h0 = 0.5f * (hh[idx] + hh[idx + 131072]);
  float c0 = 0.5f * (hc[idx] + hc[idx + 131072]);
  u16 hb = f2bf(h0);
  h1[idx] = hb; h2[idx] = hb; c1[idx] = c0; c2[idx] = c0;
}

// fused attention: e -> softmax -> context ; one block per batch. q bf16 in, ctx bf16 out.
__global__ __launch_bounds__(256) void k_attn(const u16* __restrict__ fmh,
    const u16* __restrict__ q, const float* __restrict__ sw, const float* __restrict__ sb,
    u16* __restrict__ ctx)
{
  __shared__ float qs[512], wss[512], sA[256], sR[256];
  int b = blockIdx.x, tid = threadIdx.x;
  qs[tid] = bfs(q[b * 512 + tid]); qs[tid + 256] = bfs(q[b * 512 + 256 + tid]);
  wss[tid] = sw[tid];              wss[tid + 256] = sw[tid + 256];
  __syncthreads();
  const u16* fb = fmh + (size_t)b * 512 * 256;
  float e0 = 0.f, e1 = 0.f, e2 = 0.f, e3 = 0.f;
  for (int c = 0; c < 512; c += 4){
    e0 = fmaf(tanh_(bfs(fb[(c+0)*256 + tid]) + qs[c+0]), wss[c+0], e0);
    e1 = fmaf(tanh_(bfs(fb[(c+1)*256 + tid]) + qs[c+1]), wss[c+1], e1);
    e2 = fmaf(tanh_(bfs(fb[(c+2)*256 + tid]) + qs[c+2]), wss[c+2], e2);
    e3 = fmaf(tanh_(bfs(fb[(c+3)*256 + tid]) + qs[c+3]), wss[c+3], e3);
  }
  float e = (e0 + e1) + (e2 + e3) + sb[0];
  sR[tid] = e; __syncthreads();
  #pragma unroll
  for (int off = 128; off > 0; off >>= 1){
    if (tid < off) sR[tid] = fmaxf(sR[tid], sR[tid + off]);
    __syncthreads();
  }
  float mx = sR[0]; __syncthreads();
  float ex = __expf(e - mx);
  sR[tid] = ex; __syncthreads();
  #pragma unroll
  for (int off = 128; off > 0; off >>= 1){
    if (tid < off) sR[tid] += sR[tid + off];
    __syncthreads();
  }
  float inv = 1.f / sR[0];
  sA[tid] = ex * inv; __syncthreads();
  #pragma unroll
  for (int cc = 0; cc < 2; ++cc){
    int c = tid + cc * 256;
    const u16* row = fb + (size_t)c * 256;
    float s0 = 0.f, s1 = 0.f;
    for (int h8 = 0; h8 < 32; h8 += 2){
      us8v va = *(const us8v*)(row + h8 * 8);
      us8v vb = *(const us8v*)(row + h8 * 8 + 8);
      #pragma unroll
      for (int u2 = 0; u2 < 8; ++u2){
        s0 = fmaf(sA[h8*8 + u2],     bfs(va[u2]), s0);
        s1 = fmaf(sA[h8*8 + 8 + u2], bfs(vb[u2]), s1);
      }
    }
    ctx[(size_t)b * 512 + c] = f2bf(s0 + s1);
  }
}

__global__ __launch_bounds__(256) void k_lstm(const float* __restrict__ g,
    const float* __restrict__ cp, u16* __restrict__ hn, float* __restrict__ cn,
    u16* __restrict__ hidout, int t)
{
  int idx = blockIdx.x * 256 + threadIdx.x;  // 131072
  int b = idx >> 9, j = idx & 511;
  const float* gb = g + (size_t)b * 2048;
  float iv = sigm(gb[j]);
  float fv = sigm(gb[512 + j]);
  float gv = tanh_(gb[1024 + j]);
  float ov = sigm(gb[1536 + j]);
  float c = fv * cp[idx] + iv * gv;
  float h = ov * tanh_(c);
  u16 hb = f2bf(h);
  cn[idx] = c; hn[idx] = hb;
  if (hidout) hidout[((size_t)(b * 26 + t)) * 512 + j] = hb;
}

// final projection: out[6656][38] = hid @ genw^T + gen_b. Tile 128x48, grid 52.
__global__ __launch_bounds__(256) void k_gen(const u16* __restrict__ hid,
    const u16* __restrict__ genw, const float* __restrict__ gb, float* __restrict__ out)
{
  __shared__ u16 As[128 * 32];
  __shared__ u16 Bs[48 * 32];
  int tid = threadIdx.x;
  int wave = tid >> 6, lane = tid & 63;
  int m0 = blockIdx.x * 128;
  int r = tid >> 1, seg = (tid & 1) * 16;
  int lm = lane & 15, quad = lane >> 4;
  int mw = wave * 32;
  f4v acc[2][3];
  #pragma unroll
  for (int i = 0; i < 2; ++i)
    #pragma unroll
    for (int j = 0; j < 3; ++j)
      acc[i][j] = (f4v){0.f, 0.f, 0.f, 0.f};
  const u16* aRow = hid + (size_t)(m0 + r) * 512 + seg;
  const u16* bRow = genw + (size_t)r * 512 + seg;   // valid only tid<96
  for (int kc = 0; kc < 16; ++kc){
    us8v a0 = *(const us8v*)(aRow + kc * 32);
    us8v a1 = *(const us8v*)(aRow + kc * 32 + 8);
    us8v b0, b1;
    if (tid < 96){
      b0 = *(const us8v*)(bRow + kc * 32);
      b1 = *(const us8v*)(bRow + kc * 32 + 8);
    }
    __syncthreads();
    *(us8v*)&As[r * 32 + seg]     = a0;
    *(us8v*)&As[r * 32 + seg + 8] = a1;
    if (tid < 96){
      *(us8v*)&Bs[r * 32 + seg]     = b0;
      *(us8v*)&Bs[r * 32 + seg + 8] = b1;
    }
    __syncthreads();
    bf8v af[2], bfr[3];
    #pragma unroll
    for (int i = 0; i < 2; ++i) af[i]  = *(const bf8v*)&As[(mw + i * 16 + lm) * 32 + quad * 8];
    #pragma unroll
    for (int j = 0; j < 3; ++j) bfr[j] = *(const bf8v*)&Bs[(j * 16 + lm) * 32 + quad * 8];
    #pragma unroll
    for (int i = 0; i < 2; ++i)
      #pragma unroll
      for (int j = 0; j < 3; ++j)
        acc[i][j] = __builtin_amdgcn_mfma_f32_16x16x32_bf16(af[i], bfr[j], acc[i][j], 0, 0, 0);
  }
  #pragma unroll
  for (int j = 0; j < 3; ++j){
    int n = j * 16 + lm;
    if (n >= 38) continue;
    float bv = gb[n];
    #pragma unroll
    for (int i = 0; i < 2; ++i){
      int mb = m0 + mw + i * 16 + quad * 4;
      #pragma unroll
      for (int reg = 0; reg < 4; ++reg)
        out[(size_t)(mb + reg) * 38 + n] = acc[i][j][reg] + bv;
    }
  }
}

extern "C" void kernel_launch(void* const* d_in, const int* in_sizes, int n_in,
                              void* d_out, int out_size, void* d_ws, size_t ws_size,
                              hipStream_t stream)
{
  (void)in_sizes; (void)n_in; (void)out_size; (void)ws_size;
  const float* fm      = (const float*)d_in[0];
  const float* batchH  = (const float*)d_in[1];
  const float* hh      = (const float*)d_in[2];
  const float* hc      = (const float*)d_in[3];
  const int*   text    = (const int*)d_in[4];
  const float* i2h_w   = (const float*)d_in[5];
  const float* h2h_w   = (const float*)d_in[6];
  const float* h2h_b   = (const float*)d_in[7];
  const float* cm2h_w  = (const float*)d_in[8];
  const float* cm2h_b  = (const float*)d_in[9];
  const float* ch2h_w  = (const float*)d_in[10];
  const float* ch2h_b  = (const float*)d_in[11];
  const float* score_w = (const float*)d_in[12];
  const float* score_b = (const float*)d_in[13];
  const float* r1_wih  = (const float*)d_in[14];
  const float* r1_whh  = (const float*)d_in[15];
  const float* r1_bih  = (const float*)d_in[16];
  const float* r1_bhh  = (const float*)d_in[17];
  const float* hlin_w  = (const float*)d_in[18];
  const float* hlin_b  = (const float*)d_in[19];
  const float* r2_wih  = (const float*)d_in[20];
  const float* r2_whh  = (const float*)d_in[21];
  const float* r2_bih  = (const float*)d_in[22];
  const float* r2_bhh  = (const float*)d_in[23];
  const float* gen_w   = (const float*)d_in[24];
  const float* gen_b   = (const float*)d_in[25];

  // ---- workspace layout (within proven 88.6 MB budget) ----
  char* ws = (char*)d_ws;
  u16* fmh = (u16*)(ws + 0);                 // 67,108,864 B, live whole run
  char* R  = ws + 67108864;                  // 21,495,808 B multi-phase region
  // conv phase (R fully owned by conv staging):
  u16* Wt    = (u16*)(R + 0);                // 4,718,592
  u16* chunk = (u16*)(R + 4718592);          // 16,777,216
  // steady-state (post-conv):
  u16* r1wB  = (u16*)(R + 0);                // 2,097,152  r1_wih[:, :512] bf16
  u16* r1hB  = (u16*)(R + 2097152);          // 2,097,152  r1_whh bf16
  u16* r2hB  = (u16*)(R + 4194304);          // 2,097,152  r2_whh bf16
  u16* W2cB  = (u16*)(R + 6291456);          // 2,097,152  (r2_wih @ hlin_w) bf16
  u16* WqcB  = (u16*)(R + 8388608);          //   524,288  (W1x1 @ h2h_w) bf16
  float* q_const = (float*)(R + 8912896);    //   524,288  time-invariant q part (f32)
  u16* slotA = (u16*)(R + 9437184);          //   262,144  ctx (bf16); genw overlay at epilogue
  u16* qb    = (u16*)(R + 9699328);          //   262,144  q bf16
  u16* h1a   = (u16*)(R + 9961472);          //   262,144  h1 ping
  u16* h1b   = (u16*)(R + 10223616);         //   262,144  h1 pong
  u16* h2a   = (u16*)(R + 10485760);         //   262,144  h2 ping
  u16* h2b   = (u16*)(R + 10747904);         //   262,144  h2 pong
  float* c1  = (float*)(R + 11010048);       //   524,288
  float* c2  = (float*)(R + 11534336);       //   524,288
  float* b2c = (float*)(R + 12058624);       //     8,192  folded gates2 bias
  float* qbias = (float*)(R + 12066816);     //     2,048  folded q bias
  u16* hid   = (u16*)(R + 12068864);         // 6,815,744  (b,t,hs) bf16 -> ends 18,884,608
  // precompute-only temps (overlay hid region; dead before hid is written):
  u16* r2wB    = (u16*)(R + 12068864);       // 2,097,152  r2_wih bf16
  u16* hlinT   = (u16*)(R + 14166016);       //   524,288  hlin_w^T bf16
  u16* h2hT    = (u16*)(R + 14690304);       //   524,288  h2h_w^T bf16
  u16* ch2hB   = (u16*)(R + 15214592);       //   524,288  conv_h2h 1x1 bf16
  float* bh_mean = (float*)(R + 18884608);   //   524,288  (prologue only)
  float* bh_proj = (float*)(R + 19408896);   //   524,288  (prologue only)
  // recurrence-phase overlay of bh_mean/bh_proj (dead after prologue):
  float* gbuf = (float*)(R + 18884608);      // 2,097,152  gates2 f32 -> ends 20,981,760
  u16* genw  = slotA;                        //    49,152  (epilogue overlay)

  // ---- conv phase ----
  k_wt_prep<<<9216, 256, 0, stream>>>(cm2h_w, Wt);
  for (int rb = 0; rb < 4; ++rb){
    k_transpose_fm<<<dim3(4, 8, 64), 256, 0, stream>>>(fm, chunk, rb * 64);
    k_conv<<<512, 256, 0, stream>>>(chunk, Wt, cm2h_b, fmh, rb * 64);
  }
  // ---- weight converts (overwrite conv staging) ----
  k_cvt_rw1<<<4096, 256, 0, stream>>>(r1_wih, r1wB);
  k_cvt<<<4096, 256, 0, stream>>>(r1_whh, r1hB, 1048576);
  k_cvt<<<4096, 256, 0, stream>>>(r2_whh, r2hB, 1048576);
  k_cvt<<<4096, 256, 0, stream>>>(r2_wih, r2wB, 1048576);
  k_cvt<<<1024, 256, 0, stream>>>(ch2h_w, ch2hB, 262144);
  k_cvt_t<<<dim3(16, 16), 256, 0, stream>>>(hlin_w, hlinT);
  k_cvt_t<<<dim3(16, 16), 256, 0, stream>>>(h2h_w, h2hT);
  // ---- folded weights ----
  // W2c[n][m] = sum_k r2_wih[n][k] * hlin_w[k][m]
  k_mgemm<<<dim3(4, 16), 256, 0, stream>>>(r2wB, hlinT, nullptr, nullptr,
      nullptr, nullptr, nullptr, W2cB, 1, 512);
  // Wqc[n][m] = sum_k W1x1[n][k] * h2h_w[k][m]
  k_mgemm<<<dim3(4, 4), 256, 0, stream>>>(ch2hB, h2hT, nullptr, nullptr,
      nullptr, nullptr, nullptr, WqcB, 1, 512);
  // ---- prologue ----
  k_meanH<<<512, 256, 0, stream>>>(batchH, bh_mean);
  k_pgemm<<<dim3(8, 8), 256, 0, stream>>>(bh_mean, i2h_w, bh_proj);
  // qbias[n] = ch2h_b[n] + sum_k h2h_b[k]*W1x1[n][k]
  k_bfold<<<2, 256, 0, stream>>>(ch2h_w, h2h_b, ch2h_b, nullptr, qbias, 512);
  // q_const = bh_proj @ W1x1^T (exact f32) + qbias
  k_pgemm<<<dim3(8, 8), 256, 0, stream>>>(bh_proj, ch2h_w, q_const);
  k_addrow<<<512, 256, 0, stream>>>(q_const, qbias);
  // b2c[n] = r2_bih[n] + r2_bhh[n] + sum_k r2_wih[n][k]*hlin_b[k]
  k_bfold<<<8, 256, 0, stream>>>(r2_wih, hlin_b, r2_bih, r2_bhh, b2c, 2048);
  k_init<<<512, 256, 0, stream>>>(hh, hc, h1a, c1, h2a, c2);

  // ---- 26-step recurrence: 5 kernels/step (A/B: lstm1 fused, lstm2 split) ----
  for (int t = 0; t < 26; ++t){
    u16* h1i = (t & 1) ? h1b : h1a;
    u16* h1o = (t & 1) ? h1a : h1b;
    u16* h2i = (t & 1) ? h2b : h2a;
    u16* h2o = (t & 1) ? h2a : h2b;
    // q = q_const + h2 @ Wqc^T  -> qb (bf16)
    k_mgemm<<<dim3(4, 2), 256, 0, stream>>>(h2i, WqcB, nullptr, nullptr,
        nullptr, nullptr, q_const, qb, 1, 512);
    // attention -> ctx in slotA (bf16)
    k_attn<<<256, 256, 0, stream>>>(fmh, qb, score_w, score_b, slotA);
    // gates1+lstm1 (FUSED): ctx@r1_wih[:512]^T + h1@r1_whh^T + biases + onehot -> h1o, c1
    k_glstm<<<dim3(8, 4), 256, 0, stream>>>(slotA, r1wB, h1i, r1hB,
        r1_bih, r1_bhh, r1_wih, text, t, h1o, c1, nullptr);
    // gates2 (SPLIT): h1@W2c^T + h2@r2_whh^T + b2c -> gbuf (f32)
    k_mgemm<<<dim3(16, 2), 256, 0, stream>>>(h1o, W2cB, h2i, r2hB,
        b2c, nullptr, nullptr, gbuf, 0, 2048);
    k_lstm<<<512, 256, 0, stream>>>(gbuf, c2, h2o, c2, hid, t);
  }
  // ---- final projection ----
  k_cvt_gen<<<96, 256, 0, stream>>>(gen_w, genw);
  k_gen<<<52, 256, 0, stream>>>(hid, genw, gen_b, (float*)d_out);
}

// Round 3
// 4967.142 us; speedup vs baseline: 2.8804x; 1.0481x over previous
//
#include <hip/hip_runtime.h>
#include <stdint.h>

typedef unsigned short u16;
typedef unsigned int   u32;
typedef __attribute__((ext_vector_type(8))) short bf8v;          // 8 x bf16 MFMA frag (4 VGPR)
typedef __attribute__((ext_vector_type(4))) float f4v;           // MFMA acc frag
typedef __attribute__((ext_vector_type(8))) unsigned short us8v; // 16B bf16 vector

// LDS row stride for 32-k-element bf16 rows: 40 u16 = 80 B. gcd(5,8)=1 makes
// 16B-chunk bank-group = (5*row + q) mod 8 uniform -> conflict-free b128 r/w.
#define LSTR 40

__device__ __forceinline__ float bfs(u16 u){ union { u32 i; float f; } v; v.i = ((u32)u) << 16; return v.f; }
__device__ __forceinline__ u16 f2bf(float f){ union { float f; u32 i; } v; v.f = f; u32 i = v.i; return (u16)((i + 0x7fffu + ((i >> 16) & 1u)) >> 16); }
__device__ __forceinline__ float sigm(float x){ return 1.f / (1.f + __expf(-x)); }
__device__ __forceinline__ float tanh_(float x){ float e = __expf(2.f * x); return 1.f - 2.f / (e + 1.f); }

// ---------------- one-time / chunked prep ----------------

// feature_map f32 (b,ci,hw) -> chunk bf16 (b_local,hw,ci), 64 batches at b_base
__global__ __launch_bounds__(256) void k_transpose_fm(const float* __restrict__ fm, u16* __restrict__ out, int b_base){
  __shared__ u16 tile[64][65];
  int b = blockIdx.z, hw0 = blockIdx.x * 64, ci0 = blockIdx.y * 64;
  int tid = threadIdx.x;
  int hwl = tid & 63, ci_l = tid >> 6;
  #pragma unroll
  for (int r = 0; r < 16; ++r){
    int ci = ci_l * 16 + r;
    tile[ci][hwl] = f2bf(fm[((size_t)((b_base + b) * 512 + ci0 + ci)) * 256 + hw0 + hwl]);
  }
  __syncthreads();
  int cil = tid & 63, hw_l = tid >> 6;
  #pragma unroll
  for (int r = 0; r < 16; ++r){
    int hw = hw_l * 16 + r;
    out[((size_t)(b * 256 + hw0 + hw)) * 512 + ci0 + cil] = tile[cil][hw];
  }
}

// conv_m2h_w f32 (co,ci,3,3) -> Wt bf16 (dydx,co,ci)
__global__ __launch_bounds__(256) void k_wt_prep(const float* __restrict__ w, u16* __restrict__ wt){
  int idx = blockIdx.x * 256 + threadIdx.x;         // 9*512*512
  int ci = idx & 511, co = (idx >> 9) & 511, dydx = idx >> 18;
  wt[idx] = f2bf(w[((size_t)(co * 512 + ci)) * 9 + dydx]);
}

// generic f32 -> bf16 convert
__global__ __launch_bounds__(256) void k_cvt(const float* __restrict__ src, u16* __restrict__ dst, int n){
  int idx = blockIdx.x * 256 + threadIdx.x;
  if (idx < n) dst[idx] = f2bf(src[idx]);
}
// r1_wih (2048 x 550) -> first 512 cols, bf16 [2048][512]
__global__ __launch_bounds__(256) void k_cvt_rw1(const float* __restrict__ src, u16* __restrict__ dst){
  int idx = blockIdx.x * 256 + threadIdx.x;   // 2048*512
  int n = idx >> 9, k = idx & 511;
  dst[idx] = f2bf(src[(size_t)n * 550 + k]);
}
// gen_w (38 x 512) -> bf16 [48][512] zero-padded
__global__ __launch_bounds__(256) void k_cvt_gen(const float* __restrict__ src, u16* __restrict__ dst){
  int idx = blockIdx.x * 256 + threadIdx.x;   // 48*512
  int n = idx >> 9, k = idx & 511;
  dst[idx] = (n < 38) ? f2bf(src[(size_t)n * 512 + k]) : (u16)0;
}
// transpose-convert f32 [512][512] -> bf16 [512][512]^T
__global__ __launch_bounds__(256) void k_cvt_t(const float* __restrict__ src, u16* __restrict__ dst){
  __shared__ float tile[32][33];
  int c0 = blockIdx.x * 32, r0 = blockIdx.y * 32;
  int tx = threadIdx.x & 31, ty = threadIdx.x >> 5;
  #pragma unroll
  for (int rr = ty; rr < 32; rr += 8)
    tile[rr][tx] = src[(size_t)(r0 + rr) * 512 + c0 + tx];
  __syncthreads();
  #pragma unroll
  for (int rr = ty; rr < 32; rr += 8)
    dst[(size_t)(c0 + rr) * 512 + r0 + tx] = f2bf(tile[tx][rr]);
}
// out[n] = a1[n] (+a2[n]) + sum_k W[n][k]*vin[k]   (W row length 512)
__global__ __launch_bounds__(256) void k_bfold(const float* __restrict__ W, const float* __restrict__ vin,
    const float* __restrict__ a1, const float* __restrict__ a2, float* __restrict__ out, int N){
  int n = blockIdx.x * 256 + threadIdx.x;
  if (n >= N) return;
  float s = a1 ? a1[n] : 0.f;
  if (a2) s += a2[n];
  const float* wr = W + (size_t)n * 512;
  float acc0 = 0.f, acc1 = 0.f, acc2 = 0.f, acc3 = 0.f;
  for (int k = 0; k < 512; k += 4){
    acc0 = fmaf(wr[k],   vin[k],   acc0);
    acc1 = fmaf(wr[k+1], vin[k+1], acc1);
    acc2 = fmaf(wr[k+2], vin[k+2], acc2);
    acc3 = fmaf(wr[k+3], vin[k+3], acc3);
  }
  out[n] = s + ((acc0 + acc1) + (acc2 + acc3));
}
// dst[256][512] += row[512]
__global__ __launch_bounds__(256) void k_addrow(float* __restrict__ dst, const float* __restrict__ row){
  int idx = blockIdx.x * 256 + threadIdx.x;  // 131072
  dst[idx] += row[idx & 511];
}

// ---------------- conv3x3 as implicit GEMM (MFMA bf16) ----------------
// Per launch: 64 batches. M=16384, N=512, K=9*512. Tile 128x128, BK=32.
// Flattened 144-iter loop with register prefetch; padded LDS (LSTR).
__global__ __launch_bounds__(256) void k_conv(
    const u16* __restrict__ in_t, const u16* __restrict__ Wt,
    const float* __restrict__ cbias, u16* __restrict__ fmh, int b_base)
{
  __shared__ u16 As[128 * LSTR];
  __shared__ u16 Bs[128 * LSTR];
  int tid = threadIdx.x;
  int wave = tid >> 6, lane = tid & 63;
  int nb = blockIdx.x & 3, mb = blockIdx.x >> 2;
  int m0 = mb * 128, n0 = nb * 128;
  int bb = m0 >> 8;
  int r = tid >> 1;
  int seg = (tid & 1) * 16;
  int hwl = (mb & 1) * 128 + r;
  int y = hwl >> 5, x = hwl & 31;
  const u16* aBase = in_t + ((size_t)bb * 256) * 512 + seg;
  const u16* bBase = Wt + ((size_t)(n0 + r)) * 512 + seg;
  int lm = lane & 15, quad = lane >> 4;
  int wm = (wave & 1) * 64, wn = (wave >> 1) * 64;
  f4v acc[4][4];
  #pragma unroll
  for (int i = 0; i < 4; ++i)
    #pragma unroll
    for (int j = 0; j < 4; ++j)
      acc[i][j] = (f4v){0.f, 0.f, 0.f, 0.f};

  us8v pa0, pa1, pb0, pb1;
  auto LDC = [&](int i){
    int dydx = i >> 4, kc = i & 15;
    int dy = dydx / 3, dx = dydx - dy * 3;
    int yy = y + dy - 1, xx = x + dx - 1;
    bool ok = (yy >= 0) && (yy < 8) && (xx >= 0) && (xx < 32);
    const u16* aRow = aBase + (ptrdiff_t)(yy * 32 + xx) * 512 + kc * 32;
    const u16* bRow = bBase + (size_t)dydx * 262144 + kc * 32;
    if (ok){ pa0 = *(const us8v*)aRow; pa1 = *(const us8v*)(aRow + 8); }
    else   { pa0 = (us8v){0,0,0,0,0,0,0,0}; pa1 = pa0; }
    pb0 = *(const us8v*)bRow; pb1 = *(const us8v*)(bRow + 8);
  };
  LDC(0);
  for (int i = 0; i < 144; ++i){
    __syncthreads();
    *(us8v*)&As[r * LSTR + seg]     = pa0;
    *(us8v*)&As[r * LSTR + seg + 8] = pa1;
    *(us8v*)&Bs[r * LSTR + seg]     = pb0;
    *(us8v*)&Bs[r * LSTR + seg + 8] = pb1;
    __syncthreads();
    if (i < 143) LDC(i + 1);          // loads fly during MFMA phase
    bf8v af[4], bfr[4];
    #pragma unroll
    for (int ii = 0; ii < 4; ++ii) af[ii]  = *(const bf8v*)&As[(wm + ii * 16 + lm) * LSTR + quad * 8];
    #pragma unroll
    for (int jj = 0; jj < 4; ++jj) bfr[jj] = *(const bf8v*)&Bs[(wn + jj * 16 + lm) * LSTR + quad * 8];
    #pragma unroll
    for (int ii = 0; ii < 4; ++ii)
      #pragma unroll
      for (int jj = 0; jj < 4; ++jj)
        acc[ii][jj] = __builtin_amdgcn_mfma_f32_16x16x32_bf16(af[ii], bfr[jj], acc[ii][jj], 0, 0, 0);
  }
  #pragma unroll
  for (int j = 0; j < 4; ++j){
    int co = n0 + wn + j * 16 + lm;
    float bv = cbias[co];
    #pragma unroll
    for (int i = 0; i < 4; ++i){
      int mrow = m0 + wm + i * 16 + quad * 4;
      int hw = mrow & 255;
      ushort4 pk;
      pk.x = f2bf(acc[i][j][0] + bv);
      pk.y = f2bf(acc[i][j][1] + bv);
      pk.z = f2bf(acc[i][j][2] + bv);
      pk.w = f2bf(acc[i][j][3] + bv);
      *(ushort4*)&fmh[((size_t)((b_base + bb) * 512 + co)) * 256 + hw] = pk;
    }
  }
}

// ---------------- shared pipelined 128x128 GEMM tile body ----------------
// OUT[M][N] tile at (m0,n0) = A@W^T + b1 + C0. K=512, BK=32, reg-prefetch.
__device__ __forceinline__ void gemm_tile(
    const u16* __restrict__ A, const u16* __restrict__ W,
    const float* __restrict__ b1, const float* __restrict__ C0,
    void* __restrict__ out, int obf16, int N, int m0, int n0,
    u16* As, u16* Bs)
{
  int tid = threadIdx.x;
  int wave = tid >> 6, lane = tid & 63;
  int r = tid >> 1, seg = (tid & 1) * 16;
  int lm = lane & 15, quad = lane >> 4;
  int wm = (wave & 1) * 64, wn = (wave >> 1) * 64;
  f4v acc[4][4];
  #pragma unroll
  for (int i = 0; i < 4; ++i)
    #pragma unroll
    for (int j = 0; j < 4; ++j)
      acc[i][j] = (f4v){0.f, 0.f, 0.f, 0.f};
  const u16* aRow = A + (size_t)(m0 + r) * 512 + seg;
  const u16* bRow = W + (size_t)(n0 + r) * 512 + seg;
  us8v pa0 = *(const us8v*)aRow, pa1 = *(const us8v*)(aRow + 8);
  us8v pb0 = *(const us8v*)bRow, pb1 = *(const us8v*)(bRow + 8);
  for (int kc = 0; kc < 16; ++kc){
    __syncthreads();
    *(us8v*)&As[r * LSTR + seg]     = pa0;
    *(us8v*)&As[r * LSTR + seg + 8] = pa1;
    *(us8v*)&Bs[r * LSTR + seg]     = pb0;
    *(us8v*)&Bs[r * LSTR + seg + 8] = pb1;
    __syncthreads();
    if (kc < 15){
      pa0 = *(const us8v*)(aRow + (kc + 1) * 32);
      pa1 = *(const us8v*)(aRow + (kc + 1) * 32 + 8);
      pb0 = *(const us8v*)(bRow + (kc + 1) * 32);
      pb1 = *(const us8v*)(bRow + (kc + 1) * 32 + 8);
    }
    bf8v af[4], bfr[4];
    #pragma unroll
    for (int i = 0; i < 4; ++i) af[i]  = *(const bf8v*)&As[(wm + i * 16 + lm) * LSTR + quad * 8];
    #pragma unroll
    for (int j = 0; j < 4; ++j) bfr[j] = *(const bf8v*)&Bs[(wn + j * 16 + lm) * LSTR + quad * 8];
    #pragma unroll
    for (int i = 0; i < 4; ++i)
      #pragma unroll
      for (int j = 0; j < 4; ++j)
        acc[i][j] = __builtin_amdgcn_mfma_f32_16x16x32_bf16(af[i], bfr[j], acc[i][j], 0, 0, 0);
  }
  #pragma unroll
  for (int j = 0; j < 4; ++j){
    int n = n0 + wn + j * 16 + lm;
    float badd = b1 ? b1[n] : 0.f;
    #pragma unroll
    for (int i = 0; i < 4; ++i){
      int mb = m0 + wm + i * 16 + quad * 4;
      #pragma unroll
      for (int reg = 0; reg < 4; ++reg){
        int m = mb + reg;
        float v = acc[i][j][reg] + badd;
        if (C0) v += C0[(size_t)m * N + n];
        if (obf16) ((u16*)out)[(size_t)m * N + n] = f2bf(v);
        else       ((float*)out)[(size_t)m * N + n] = v;
      }
    }
  }
}

// generic wrapper (precompute GEMMs): grid(N/128, M/128)
__global__ __launch_bounds__(256) void k_mgemm(
    const u16* __restrict__ A, const u16* __restrict__ W,
    const float* __restrict__ b1, const float* __restrict__ C0,
    void* __restrict__ out, int obf16, int N)
{
  __shared__ u16 As[128 * LSTR];
  __shared__ u16 Bs[128 * LSTR];
  gemm_tile(A, W, b1, C0, out, obf16, N, blockIdx.y * 128, blockIdx.x * 128, As, Bs);
}

// merged per-step launch: blocks 0..7 -> q = q_const + h2@Wqc^T (bf16)
//                         blocks 8..39 -> gbuf = h2@r2_whh^T + b2c (f32)
__global__ __launch_bounds__(256) void k_dual(
    const u16* __restrict__ h2,
    const u16* __restrict__ Wqc, const float* __restrict__ q_const, u16* __restrict__ qb,
    const u16* __restrict__ r2h, const float* __restrict__ b2c, float* __restrict__ gbuf)
{
  __shared__ u16 As[128 * LSTR];
  __shared__ u16 Bs[128 * LSTR];
  int bx = blockIdx.x;
  if (bx < 8){
    gemm_tile(h2, Wqc, nullptr, q_const, qb, 1, 512, (bx >> 2) * 128, (bx & 3) * 128, As, Bs);
  } else {
    int b = bx - 8;
    gemm_tile(h2, r2h, b2c, nullptr, gbuf, 0, 2048, (b >> 4) * 128, (b & 15) * 128, As, Bs);
  }
}

// ---------------- fused gates GEMM + LSTM (pipelined) ----------------
// Block = 64 batches x 64 hidden cols. Wave w computes gate w. grid(8,4)=32.
// OUT gates = A1@W1^T (+A2@W2^T) + b1 + b2 + C0(f32 [256][2048]) + onehot.
__global__ __launch_bounds__(256, 1) void k_glstm(
    const u16* __restrict__ A1, const u16* __restrict__ W1,
    const u16* __restrict__ A2, const u16* __restrict__ W2,
    const float* __restrict__ b1, const float* __restrict__ b2,
    const float* __restrict__ C0,
    const float* __restrict__ Woh, const int* __restrict__ txt, int t,
    u16* __restrict__ hn, float* __restrict__ c_io,
    u16* __restrict__ hidout)
{
  __shared__ u16 As[64 * LSTR];    // 5120 B
  __shared__ u16 Bs[256 * LSTR];   // 20480 B (f32 gate-exchange in epilogue, 16 KB used)
  int tid = threadIdx.x;
  int wave = tid >> 6, lane = tid & 63;
  int lm = lane & 15, quad = lane >> 4;
  int m0 = blockIdx.y * 64, j0 = blockIdx.x * 64;
  int sr = tid >> 2;            // 0..63
  int sseg = (tid & 3) * 8;     // u16 offset
  f4v acc[4][4];
  #pragma unroll
  for (int i = 0; i < 4; ++i)
    #pragma unroll
    for (int j = 0; j < 4; ++j)
      acc[i][j] = (f4v){0.f, 0.f, 0.f, 0.f};

  const u16* a0P = A1 + (size_t)(m0 + sr) * 512 + sseg;
  const u16* b0P0 = W1 + (size_t)(0 * 512 + j0 + sr) * 512 + sseg;
  const u16* b0P1 = W1 + (size_t)(1 * 512 + j0 + sr) * 512 + sseg;
  const u16* b0P2 = W1 + (size_t)(2 * 512 + j0 + sr) * 512 + sseg;
  const u16* b0P3 = W1 + (size_t)(3 * 512 + j0 + sr) * 512 + sseg;
  const u16* a1P  = A2 ? A2 + (size_t)(m0 + sr) * 512 + sseg : a0P;
  const u16* b1P0 = A2 ? W2 + (size_t)(0 * 512 + j0 + sr) * 512 + sseg : b0P0;
  const u16* b1P1 = A2 ? W2 + (size_t)(1 * 512 + j0 + sr) * 512 + sseg : b0P1;
  const u16* b1P2 = A2 ? W2 + (size_t)(2 * 512 + j0 + sr) * 512 + sseg : b0P2;
  const u16* b1P3 = A2 ? W2 + (size_t)(3 * 512 + j0 + sr) * 512 + sseg : b0P3;
  int nit = A2 ? 32 : 16;

  us8v pav, pb0, pb1, pb2, pb3;
  auto LDG = [&](int i){
    int ps = i >> 4, kc = i & 15;
    const u16* ap  = ps ? a1P  : a0P;
    const u16* bp0 = ps ? b1P0 : b0P0;
    const u16* bp1 = ps ? b1P1 : b0P1;
    const u16* bp2 = ps ? b1P2 : b0P2;
    const u16* bp3 = ps ? b1P3 : b0P3;
    pav = *(const us8v*)(ap  + kc * 32);
    pb0 = *(const us8v*)(bp0 + kc * 32);
    pb1 = *(const us8v*)(bp1 + kc * 32);
    pb2 = *(const us8v*)(bp2 + kc * 32);
    pb3 = *(const us8v*)(bp3 + kc * 32);
  };
  LDG(0);
  for (int i = 0; i < nit; ++i){
    __syncthreads();
    *(us8v*)&As[sr * LSTR + sseg]              = pav;
    *(us8v*)&Bs[(0 * 64 + sr) * LSTR + sseg]   = pb0;
    *(us8v*)&Bs[(1 * 64 + sr) * LSTR + sseg]   = pb1;
    *(us8v*)&Bs[(2 * 64 + sr) * LSTR + sseg]   = pb2;
    *(us8v*)&Bs[(3 * 64 + sr) * LSTR + sseg]   = pb3;
    __syncthreads();
    if (i + 1 < nit) LDG(i + 1);
    bf8v af[4], bfr[4];
    #pragma unroll
    for (int mi = 0; mi < 4; ++mi) af[mi]  = *(const bf8v*)&As[(mi * 16 + lm) * LSTR + quad * 8];
    #pragma unroll
    for (int nj = 0; nj < 4; ++nj) bfr[nj] = *(const bf8v*)&Bs[(wave * 64 + nj * 16 + lm) * LSTR + quad * 8];
    #pragma unroll
    for (int mi = 0; mi < 4; ++mi)
      #pragma unroll
      for (int nj = 0; nj < 4; ++nj)
        acc[mi][nj] = __builtin_amdgcn_mfma_f32_16x16x32_bf16(af[mi], bfr[nj], acc[mi][nj], 0, 0, 0);
  }

  // epilogue: 4 chunks of 16 batch-rows; gate exchange via LDS; fully unrolled
  float* gL = (float*)Bs;   // [4 gates][16 rows][64 cols] f32 = 16 KB
  #pragma unroll
  for (int mi = 0; mi < 4; ++mi){
    __syncthreads();
    #pragma unroll
    for (int nj = 0; nj < 4; ++nj)
      #pragma unroll
      for (int reg = 0; reg < 4; ++reg)
        gL[wave * 1024 + (quad * 4 + reg) * 64 + nj * 16 + lm] = acc[mi][nj][reg];
    __syncthreads();
    #pragma unroll
    for (int p = 0; p < 4; ++p){
      int idx = p * 256 + tid;          // 16*64 = 1024 outputs
      int bl = idx >> 6, jj = idx & 63;
      int b = m0 + mi * 16 + bl;
      int j = j0 + jj;
      float gi = gL[idx];
      float gf = gL[1024 + idx];
      float gg = gL[2048 + idx];
      float go = gL[3072 + idx];
      if (b1){ gi += b1[j]; gf += b1[512 + j]; gg += b1[1024 + j]; go += b1[1536 + j]; }
      if (b2){ gi += b2[j]; gf += b2[512 + j]; gg += b2[1024 + j]; go += b2[1536 + j]; }
      if (C0){
        const float* cb = C0 + (size_t)b * 2048 + j;
        gi += cb[0]; gf += cb[512]; gg += cb[1024]; go += cb[1536];
      }
      if (Woh){
        int tx = txt[b * 26 + t];
        gi += Woh[(size_t)j * 550 + 512 + tx];
        gf += Woh[(size_t)(512 + j) * 550 + 512 + tx];
        gg += Woh[(size_t)(1024 + j) * 550 + 512 + tx];
        go += Woh[(size_t)(1536 + j) * 550 + 512 + tx];
      }
      float iv = sigm(gi), fv = sigm(gf), gv = tanh_(gg), ov = sigm(go);
      float c = fv * c_io[(size_t)b * 512 + j] + iv * gv;
      float h = ov * tanh_(c);
      c_io[(size_t)b * 512 + j] = c;
      u16 hb = f2bf(h);
      hn[(size_t)b * 512 + j] = hb;
      if (hidout) hidout[((size_t)(b * 26 + t)) * 512 + j] = hb;
    }
  }
}

// ---------------- small dense ops ----------------

__global__ __launch_bounds__(256) void k_meanH(const float* __restrict__ H, float* __restrict__ outm){
  int idx = blockIdx.x * 256 + threadIdx.x;  // 256*512
  int b = idx >> 9, k = idx & 511;
  float s = 0.f;
  #pragma unroll
  for (int t = 0; t < 26; ++t) s += H[((size_t)(b * 26 + t)) * 512 + k];
  outm[idx] = s * (1.f / 26.f);
}

// one-off f32 VALU GEMM: out[256][512] = A[256][512] @ W[512][512]^T (raw f32)
__global__ __launch_bounds__(256) void k_pgemm(const float* __restrict__ A, const float* __restrict__ W,
                                               float* __restrict__ out){
  __shared__ float As[32][33];
  __shared__ float Ws[64][33];
  int tid = threadIdx.x;
  int n0 = blockIdx.x * 64, m0 = blockIdx.y * 32;
  float acc[2][4] = {{0.f,0.f,0.f,0.f},{0.f,0.f,0.f,0.f}};
  int ml = (tid >> 4) * 2, nl = (tid & 15) * 4;
  int sm = tid >> 3, sk = (tid & 7) * 4;
  int wn = tid >> 2, wk = (tid & 3) * 8;
  for (int k0 = 0; k0 < 512; k0 += 32){
    __syncthreads();
    float4 av = *(const float4*)&A[(size_t)(m0 + sm) * 512 + k0 + sk];
    As[sm][sk] = av.x; As[sm][sk+1] = av.y; As[sm][sk+2] = av.z; As[sm][sk+3] = av.w;
    const float* wp = W + (size_t)(n0 + wn) * 512 + k0 + wk;
    #pragma unroll
    for (int u2 = 0; u2 < 8; ++u2) Ws[wn][wk + u2] = wp[u2];
    __syncthreads();
    #pragma unroll
    for (int k = 0; k < 32; ++k){
      float a0 = As[ml][k], a1 = As[ml+1][k];
      float w0 = Ws[nl][k], w1 = Ws[nl+1][k], w2 = Ws[nl+2][k], w3 = Ws[nl+3][k];
      acc[0][0] = fmaf(a0,w0,acc[0][0]); acc[0][1] = fmaf(a0,w1,acc[0][1]);
      acc[0][2] = fmaf(a0,w2,acc[0][2]); acc[0][3] = fmaf(a0,w3,acc[0][3]);
      acc[1][0] = fmaf(a1,w0,acc[1][0]); acc[1][1] = fmaf(a1,w1,acc[1][1]);
      acc[1][2] = fmaf(a1,w2,acc[1][2]); acc[1][3] = fmaf(a1,w3,acc[1][3]);
    }
  }
  #pragma unroll
  for (int i = 0; i < 2; ++i)
    #pragma unroll
    for (int j = 0; j < 4; ++j)
      out[(size_t)(m0 + ml + i) * 512 + n0 + nl + j] = acc[i][j];
}

__global__ __launch_bounds__(256) void k_init(const float* __restrict__ hh, const float* __restrict__ hc,
                                              u16* h1, float* c1, u16* h2, float* c2){
  int idx = blockIdx.x * 256 + threadIdx.x;  // 131072
  float h0 = 0.5f * (hh[idx] + hh[idx + 131072]);
  float c0 = 0.5f * (hc[idx] + hc[idx + 131072]);
  u16 hb = f2bf(h0);
  h1[idx] = hb; h2[idx] = hb; c1[idx] = c0; c2[idx] = c0;
}

// fused attention: e -> softmax -> context ; one block per batch. q bf16 in, ctx bf16 out.
__global__ __launch_bounds__(256) void k_attn(const u16* __restrict__ fmh,
    const u16* __restrict__ q, const float* __restrict__ sw, const float* __restrict__ sb,
    u16* __restrict__ ctx)
{
  __shared__ float qs[512], wss[512], sA[256], sR[256];
  int b = blockIdx.x, tid = threadIdx.x;
  qs[tid] = bfs(q[b * 512 + tid]); qs[tid + 256] = bfs(q[b * 512 + 256 + tid]);
  wss[tid] = sw[tid];              wss[tid + 256] = sw[tid + 256];
  __syncthreads();
  const u16* fb = fmh + (size_t)b * 512 * 256;
  float e0 = 0.f, e1 = 0.f, e2 = 0.f, e3 = 0.f;
  for (int c = 0; c < 512; c += 4){
    e0 = fmaf(tanh_(bfs(fb[(c+0)*256 + tid]) + qs[c+0]), wss[c+0], e0);
    e1 = fmaf(tanh_(bfs(fb[(c+1)*256 + tid]) + qs[c+1]), wss[c+1], e1);
    e2 = fmaf(tanh_(bfs(fb[(c+2)*256 + tid]) + qs[c+2]), wss[c+2], e2);
    e3 = fmaf(tanh_(bfs(fb[(c+3)*256 + tid]) + qs[c+3]), wss[c+3], e3);
  }
  float e = (e0 + e1) + (e2 + e3) + sb[0];
  sR[tid] = e; __syncthreads();
  #pragma unroll
  for (int off = 128; off > 0; off >>= 1){
    if (tid < off) sR[tid] = fmaxf(sR[tid], sR[tid + off]);
    __syncthreads();
  }
  float mx = sR[0]; __syncthreads();
  float ex = __expf(e - mx);
  sR[tid] = ex; __syncthreads();
  #pragma unroll
  for (int off = 128; off > 0; off >>= 1){
    if (tid < off) sR[tid] += sR[tid + off];
    __syncthreads();
  }
  float inv = 1.f / sR[0];
  sA[tid] = ex * inv; __syncthreads();
  #pragma unroll
  for (int cc = 0; cc < 2; ++cc){
    int c = tid + cc * 256;
    const u16* row = fb + (size_t)c * 256;
    float s0 = 0.f, s1 = 0.f;
    for (int h8 = 0; h8 < 32; h8 += 2){
      us8v va = *(const us8v*)(row + h8 * 8);
      us8v vb = *(const us8v*)(row + h8 * 8 + 8);
      #pragma unroll
      for (int u2 = 0; u2 < 8; ++u2){
        s0 = fmaf(sA[h8*8 + u2],     bfs(va[u2]), s0);
        s1 = fmaf(sA[h8*8 + 8 + u2], bfs(vb[u2]), s1);
      }
    }
    ctx[(size_t)b * 512 + c] = f2bf(s0 + s1);
  }
}

// final projection: out[6656][38] = hid @ genw^T + gen_b. Tile 128x48, grid 52.
__global__ __launch_bounds__(256) void k_gen(const u16* __restrict__ hid,
    const u16* __restrict__ genw, const float* __restrict__ gb, float* __restrict__ out)
{
  __shared__ u16 As[128 * LSTR];
  __shared__ u16 Bs[48 * LSTR];
  int tid = threadIdx.x;
  int wave = tid >> 6, lane = tid & 63;
  int m0 = blockIdx.x * 128;
  int r = tid >> 1, seg = (tid & 1) * 16;
  int lm = lane & 15, quad = lane >> 4;
  int mw = wave * 32;
  f4v acc[2][3];
  #pragma unroll
  for (int i = 0; i < 2; ++i)
    #pragma unroll
    for (int j = 0; j < 3; ++j)
      acc[i][j] = (f4v){0.f, 0.f, 0.f, 0.f};
  const u16* aRow = hid + (size_t)(m0 + r) * 512 + seg;
  const u16* bRow = genw + (size_t)r * 512 + seg;   // valid only tid<96
  us8v pa0 = *(const us8v*)aRow, pa1 = *(const us8v*)(aRow + 8);
  us8v pb0, pb1;
  if (tid < 96){ pb0 = *(const us8v*)bRow; pb1 = *(const us8v*)(bRow + 8); }
  for (int kc = 0; kc < 16; ++kc){
    __syncthreads();
    *(us8v*)&As[r * LSTR + seg]     = pa0;
    *(us8v*)&As[r * LSTR + seg + 8] = pa1;
    if (tid < 96){
      *(us8v*)&Bs[r * LSTR + seg]     = pb0;
      *(us8v*)&Bs[r * LSTR + seg + 8] = pb1;
    }
    __syncthreads();
    if (kc < 15){
      pa0 = *(const us8v*)(aRow + (kc + 1) * 32);
      pa1 = *(const us8v*)(aRow + (kc + 1) * 32 + 8);
      if (tid < 96){
        pb0 = *(const us8v*)(bRow + (kc + 1) * 32);
        pb1 = *(const us8v*)(bRow + (kc + 1) * 32 + 8);
      }
    }
    bf8v af[2], bfr[3];
    #pragma unroll
    for (int i = 0; i < 2; ++i) af[i]  = *(const bf8v*)&As[(mw + i * 16 + lm) * LSTR + quad * 8];
    #pragma unroll
    for (int j = 0; j < 3; ++j) bfr[j] = *(const bf8v*)&Bs[(j * 16 + lm) * LSTR + quad * 8];
    #pragma unroll
    for (int i = 0; i < 2; ++i)
      #pragma unroll
      for (int j = 0; j < 3; ++j)
        acc[i][j] = __builtin_amdgcn_mfma_f32_16x16x32_bf16(af[i], bfr[j], acc[i][j], 0, 0, 0);
  }
  #pragma unroll
  for (int j = 0; j < 3; ++j){
    int n = j * 16 + lm;
    if (n >= 38) continue;
    float bv = gb[n];
    #pragma unroll
    for (int i = 0; i < 2; ++i){
      int mb = m0 + mw + i * 16 + quad * 4;
      #pragma unroll
      for (int reg = 0; reg < 4; ++reg)
        out[(size_t)(mb + reg) * 38 + n] = acc[i][j][reg] + bv;
    }
  }
}

extern "C" void kernel_launch(void* const* d_in, const int* in_sizes, int n_in,
                              void* d_out, int out_size, void* d_ws, size_t ws_size,
                              hipStream_t stream)
{
  (void)in_sizes; (void)n_in; (void)out_size; (void)ws_size;
  const float* fm      = (const float*)d_in[0];
  const float* batchH  = (const float*)d_in[1];
  const float* hh      = (const float*)d_in[2];
  const float* hc      = (const float*)d_in[3];
  const int*   text    = (const int*)d_in[4];
  const float* i2h_w   = (const float*)d_in[5];
  const float* h2h_w   = (const float*)d_in[6];
  const float* h2h_b   = (const float*)d_in[7];
  const float* cm2h_w  = (const float*)d_in[8];
  const float* cm2h_b  = (const float*)d_in[9];
  const float* ch2h_w  = (const float*)d_in[10];
  const float* ch2h_b  = (const float*)d_in[11];
  const float* score_w = (const float*)d_in[12];
  const float* score_b = (const float*)d_in[13];
  const float* r1_wih  = (const float*)d_in[14];
  const float* r1_whh  = (const float*)d_in[15];
  const float* r1_bih  = (const float*)d_in[16];
  const float* r1_bhh  = (const float*)d_in[17];
  const float* hlin_w  = (const float*)d_in[18];
  const float* hlin_b  = (const float*)d_in[19];
  const float* r2_wih  = (const float*)d_in[20];
  const float* r2_whh  = (const float*)d_in[21];
  const float* r2_bih  = (const float*)d_in[22];
  const float* r2_bhh  = (const float*)d_in[23];
  const float* gen_w   = (const float*)d_in[24];
  const float* gen_b   = (const float*)d_in[25];

  // ---- workspace layout (within proven 88.6 MB budget) ----
  char* ws = (char*)d_ws;
  u16* fmh = (u16*)(ws + 0);                 // 67,108,864 B, live whole run
  char* R  = ws + 67108864;                  // 21,495,808 B multi-phase region
  // conv phase (R fully owned by conv staging):
  u16* Wt    = (u16*)(R + 0);                // 4,718,592
  u16* chunk = (u16*)(R + 4718592);          // 16,777,216
  // steady-state (post-conv):
  u16* r1wB  = (u16*)(R + 0);                // 2,097,152  r1_wih[:, :512] bf16
  u16* r1hB  = (u16*)(R + 2097152);          // 2,097,152  r1_whh bf16
  u16* r2hB  = (u16*)(R + 4194304);          // 2,097,152  r2_whh bf16
  u16* W2cB  = (u16*)(R + 6291456);          // 2,097,152  (r2_wih @ hlin_w) bf16
  u16* WqcB  = (u16*)(R + 8388608);          //   524,288  (W1x1 @ h2h_w) bf16
  float* q_const = (float*)(R + 8912896);    //   524,288  time-invariant q part (f32)
  u16* slotA = (u16*)(R + 9437184);          //   262,144  ctx (bf16); genw overlay at epilogue
  u16* qb    = (u16*)(R + 9699328);          //   262,144  q bf16
  u16* h1a   = (u16*)(R + 9961472);          //   262,144  h1 ping
  u16* h1b   = (u16*)(R + 10223616);         //   262,144  h1 pong
  u16* h2a   = (u16*)(R + 10485760);         //   262,144  h2 ping
  u16* h2b   = (u16*)(R + 10747904);         //   262,144  h2 pong
  float* c1  = (float*)(R + 11010048);       //   524,288
  float* c2  = (float*)(R + 11534336);       //   524,288
  float* b2c = (float*)(R + 12058624);       //     8,192  folded gates2 bias
  float* qbias = (float*)(R + 12066816);     //     2,048  folded q bias
  u16* hid   = (u16*)(R + 12068864);         // 6,815,744  (b,t,hs) bf16 -> ends 18,884,608
  // precompute-only temps (overlay hid region; dead before hid is written):
  u16* r2wB    = (u16*)(R + 12068864);       // 2,097,152  r2_wih bf16
  u16* hlinT   = (u16*)(R + 14166016);       //   524,288  hlin_w^T bf16
  u16* h2hT    = (u16*)(R + 14690304);       //   524,288  h2h_w^T bf16
  u16* ch2hB   = (u16*)(R + 15214592);       //   524,288  conv_h2h 1x1 bf16
  float* bh_mean = (float*)(R + 18884608);   //   524,288  (prologue only)
  float* bh_proj = (float*)(R + 19408896);   //   524,288  (prologue only)
  // recurrence-phase overlay of bh_mean/bh_proj (dead after prologue):
  float* gbuf = (float*)(R + 18884608);      // 2,097,152  gates2 partial f32 -> ends 20,981,760
  u16* genw  = slotA;                        //    49,152  (epilogue overlay)

  // ---- conv phase ----
  k_wt_prep<<<9216, 256, 0, stream>>>(cm2h_w, Wt);
  for (int rb = 0; rb < 4; ++rb){
    k_transpose_fm<<<dim3(4, 8, 64), 256, 0, stream>>>(fm, chunk, rb * 64);
    k_conv<<<512, 256, 0, stream>>>(chunk, Wt, cm2h_b, fmh, rb * 64);
  }
  // ---- weight converts (overwrite conv staging) ----
  k_cvt_rw1<<<4096, 256, 0, stream>>>(r1_wih, r1wB);
  k_cvt<<<4096, 256, 0, stream>>>(r1_whh, r1hB, 1048576);
  k_cvt<<<4096, 256, 0, stream>>>(r2_whh, r2hB, 1048576);
  k_cvt<<<4096, 256, 0, stream>>>(r2_wih, r2wB, 1048576);
  k_cvt<<<1024, 256, 0, stream>>>(ch2h_w, ch2hB, 262144);
  k_cvt_t<<<dim3(16, 16), 256, 0, stream>>>(hlin_w, hlinT);
  k_cvt_t<<<dim3(16, 16), 256, 0, stream>>>(h2h_w, h2hT);
  // ---- folded weights ----
  // W2c[n][m] = sum_k r2_wih[n][k] * hlin_w[k][m]
  k_mgemm<<<dim3(4, 16), 256, 0, stream>>>(r2wB, hlinT, nullptr, nullptr, W2cB, 1, 512);
  // Wqc[n][m] = sum_k W1x1[n][k] * h2h_w[k][m]
  k_mgemm<<<dim3(4, 4), 256, 0, stream>>>(ch2hB, h2hT, nullptr, nullptr, WqcB, 1, 512);
  // ---- prologue ----
  k_meanH<<<512, 256, 0, stream>>>(batchH, bh_mean);
  k_pgemm<<<dim3(8, 8), 256, 0, stream>>>(bh_mean, i2h_w, bh_proj);
  // qbias[n] = ch2h_b[n] + sum_k h2h_b[k]*W1x1[n][k]
  k_bfold<<<2, 256, 0, stream>>>(ch2h_w, h2h_b, ch2h_b, nullptr, qbias, 512);
  // q_const = bh_proj @ W1x1^T (exact f32) + qbias
  k_pgemm<<<dim3(8, 8), 256, 0, stream>>>(bh_proj, ch2h_w, q_const);
  k_addrow<<<512, 256, 0, stream>>>(q_const, qbias);
  // b2c[n] = r2_bih[n] + r2_bhh[n] + sum_k r2_wih[n][k]*hlin_b[k]
  k_bfold<<<8, 256, 0, stream>>>(r2_wih, hlin_b, r2_bih, r2_bhh, b2c, 2048);
  k_init<<<512, 256, 0, stream>>>(hh, hc, h1a, c1, h2a, c2);

  // ---- 26-step recurrence: 4 kernels/step ----
  for (int t = 0; t < 26; ++t){
    u16* h1i = (t & 1) ? h1b : h1a;
    u16* h1o = (t & 1) ? h1a : h1b;
    u16* h2i = (t & 1) ? h2b : h2a;
    u16* h2o = (t & 1) ? h2a : h2b;
    // q = q_const + h2@Wqc^T (blocks 0..7) AND gbuf = h2@r2_whh^T + b2c (blocks 8..39)
    k_dual<<<40, 256, 0, stream>>>(h2i, WqcB, q_const, qb, r2hB, b2c, gbuf);
    // attention -> ctx in slotA (bf16)
    k_attn<<<256, 256, 0, stream>>>(fmh, qb, score_w, score_b, slotA);
    // gates1+lstm1 (fused 2-pass): ctx@r1w^T + h1@r1h^T + biases + onehot -> h1o, c1
    k_glstm<<<dim3(8, 4), 256, 0, stream>>>(slotA, r1wB, h1i, r1hB,
        r1_bih, r1_bhh, nullptr, r1_wih, text, t, h1o, c1, nullptr);
    // gates2+lstm2 (fused 1-pass + C0): h1o@W2c^T + gbuf -> h2o, c2, hid
    k_glstm<<<dim3(8, 4), 256, 0, stream>>>(h1o, W2cB, nullptr, nullptr,
        nullptr, nullptr, gbuf, nullptr, nullptr, t, h2o, c2, hid);
  }
  // ---- final projection ----
  k_cvt_gen<<<96, 256, 0, stream>>>(gen_w, genw);
  k_gen<<<52, 256, 0, stream>>>(hid, genw, gen_b, (float*)d_out);
}